// Round 5
// baseline (530.513 us; speedup 1.0000x reference)
//
#include <hip/hip_runtime.h>
#include <hip/hip_bf16.h>

#define NN 40000
#define EE 640000
#define ET 680000   // EE + NN self loops
#define MPAD 40064  // 313 * 128
#define LOG2E 1.4426950408889634f

typedef __attribute__((ext_vector_type(8))) short short8;
typedef __attribute__((ext_vector_type(4))) float f32x4;

__device__ __forceinline__ float bf2f(unsigned u) {
    return __uint_as_float(u << 16);
}
__device__ __forceinline__ unsigned short f2bf(float f) {
    unsigned u = __float_as_uint(f);
    return (unsigned short)((u + 0x7FFFu + ((u >> 16) & 1u)) >> 16);
}
__device__ __forceinline__ unsigned pack2(float lo, float hi) {
    return ((unsigned)f2bf(lo)) | (((unsigned)f2bf(hi)) << 16);
}
__device__ __forceinline__ void unpack2(unsigned u, float& lo, float& hi) {
    lo = __uint_as_float(u << 16);
    hi = __uint_as_float(u & 0xffff0000u);
}

// ---------------- converts ----------------
__global__ __launch_bounds__(256) void conv_x(const float* __restrict__ x,
                                              unsigned short* __restrict__ xb)
{
    int i = blockIdx.x * 256 + threadIdx.x;          // one per 4 elems
    if (i >= MPAD * 128 / 4) return;
    int row = (i * 4) >> 7;
    ushort4 o;
    if (row < NN) {
        float4 v = ((const float4*)x)[i];
        o.x = f2bf(v.x); o.y = f2bf(v.y); o.z = f2bf(v.z); o.w = f2bf(v.w);
    } else { o.x = o.y = o.z = o.w = 0; }
    ((ushort4*)xb)[i] = o;
}

// W[K][256] f32 -> Wt[256][K] bf16
__global__ __launch_bounds__(256) void conv_wt(const float* __restrict__ W,
                                               unsigned short* __restrict__ Wt, int K)
{
    int i = blockIdx.x * 256 + threadIdx.x;
    if (i >= K * 256) return;
    int c = i / K, k = i - c * K;
    Wt[i] = f2bf(W[(size_t)k * 256 + c]);
}

// ---------------- MFMA GEMM: Cd[MPAD][256] = A[MPAD][K] @ Bt^T (dual output) ----------
// Btc is [NCOLS][K] bf16 pre-transposed. Grid y covers NCOLS/128 column blocks;
// cb<256 -> C0, else C1 (cols cb-256). Block 128x128, 4 waves 2x2, wave 64x64.
__global__ __launch_bounds__(256) void gemm_bf16(
    const unsigned short* __restrict__ A, const unsigned short* __restrict__ Btc,
    unsigned short* __restrict__ C0, unsigned short* __restrict__ C1, int K)
{
    __shared__ unsigned short As[128 * 64];
    int tid = threadIdx.x;
    int rb = blockIdx.x * 128, cb = blockIdx.y * 128;
    int lane = tid & 63, wid = tid >> 6;
    int wm = (wid >> 1) * 64, wn = (wid & 1) * 64;
    int lr = lane & 15, lk = lane >> 4;
    f32x4 acc[4][4] = {};
    for (int kb = 0; kb < K; kb += 64) {
        #pragma unroll
        for (int i = 0; i < 4; i++) {
            int flat = tid + i * 256;
            int r = flat >> 3, c8 = flat & 7;
            int4 v = *(const int4*)(A + (size_t)(rb + r) * K + kb + c8 * 8);
            *(int4*)(&As[r * 64 + ((c8 ^ (r & 7)) * 8)]) = v;
        }
        __syncthreads();
        #pragma unroll
        for (int kk = 0; kk < 2; kk++) {
            int kbase = kb + kk * 32 + lk * 8;
            short8 bfr[4], afr[4];
            #pragma unroll
            for (int n = 0; n < 4; n++)
                bfr[n] = *(const short8*)(Btc + (size_t)(cb + wn + n * 16 + lr) * K + kbase);
            #pragma unroll
            for (int m = 0; m < 4; m++) {
                int row = wm + m * 16 + lr;
                int kchunk = kk * 4 + lk;
                afr[m] = *(const short8*)(&As[row * 64 + ((kchunk ^ (row & 7)) * 8)]);
            }
            #pragma unroll
            for (int m = 0; m < 4; m++)
                #pragma unroll
                for (int n = 0; n < 4; n++)
                    acc[m][n] = __builtin_amdgcn_mfma_f32_16x16x32_bf16(afr[m], bfr[n], acc[m][n], 0, 0, 0);
        }
        __syncthreads();
    }
    unsigned short* C = (cb < 256) ? C0 : C1;
    int cbase = cb & 255;
    #pragma unroll
    for (int m = 0; m < 4; m++)
        #pragma unroll
        for (int n = 0; n < 4; n++) {
            int col = cbase + wn + n * 16 + lr;
            #pragma unroll
            for (int j = 0; j < 4; j++) {
                int row = rb + wm + m * 16 + lk * 4 + j;
                C[(size_t)row * 256 + col] = f2bf(acc[m][n][j]);
            }
        }
}

// ---------------- CSR build (by dst) ----------------
__global__ __launch_bounds__(256) void csr_count(const int* __restrict__ ei, int* __restrict__ deg)
{
    int e = blockIdx.x * blockDim.x + threadIdx.x;
    if (e >= ET) return;
    int d = (e < EE) ? ei[EE + e] : (e - EE);
    atomicAdd(&deg[d], 1);
}

__global__ __launch_bounds__(1024) void exscan(
    const int* __restrict__ deg, int* __restrict__ rowptr, int* __restrict__ cursor)
{
    __shared__ int wsum[16];
    __shared__ int carry_s;
    int tid = threadIdx.x, lane = tid & 63, wid = tid >> 6;
    if (tid == 0) carry_s = 0;
    __syncthreads();
    for (int base = 0; base < NN; base += 1024) {
        int i = base + tid;
        int v = (i < NN) ? deg[i] : 0;
        int sc = v;
        #pragma unroll
        for (int off = 1; off < 64; off <<= 1) {
            int t = __shfl_up(sc, off);
            if (lane >= off) sc += t;
        }
        if (lane == 63) wsum[wid] = sc;
        __syncthreads();
        if (wid == 0 && lane < 16) {
            int t = wsum[lane];
            #pragma unroll
            for (int off = 1; off < 16; off <<= 1) {
                int u = __shfl_up(t, off);
                if (lane >= off) t += u;
            }
            wsum[lane] = t;
        }
        __syncthreads();
        int carry = carry_s;
        int wpre = wid ? wsum[wid - 1] : 0;
        int excl = carry + wpre + sc - v;
        if (i < NN) { rowptr[i] = excl; cursor[i] = excl; }
        __syncthreads();
        if (tid == 0) carry_s = carry + wsum[15];
    }
    if (tid == 0) rowptr[NN] = carry_s;
}

__global__ __launch_bounds__(256) void csr_fill(
    const int* __restrict__ ei, int* __restrict__ cursor, int* __restrict__ adj)
{
    int e = blockIdx.x * blockDim.x + threadIdx.x;
    if (e >= ET) return;
    int s, d;
    if (e < EE) { s = ei[e]; d = ei[EE + e]; } else { s = d = e - EE; }
    int pos = atomicAdd(&cursor[d], 1);
    adj[pos] = s;
}

// ---------------- attention logits (pre-scaled by log2(e)) ----------------
__global__ __launch_bounds__(256) void attn_node0(
    const unsigned short* __restrict__ xp, const float* __restrict__ att_s,
    const float* __restrict__ att_d, float* __restrict__ a_s, float* __restrict__ a_d)
{
    int t = blockIdx.x * 256 + threadIdx.x;
    if (t >= NN * 8) return;
    int n = t >> 3, h = t & 7;
    const unsigned short* p = xp + (size_t)n * 256 + h * 32;
    float s = 0.f, dd = 0.f;
    #pragma unroll
    for (int i0 = 0; i0 < 32; i0 += 8) {
        uint4 raw = *(const uint4*)(p + i0);
        unsigned vals[4] = {raw.x, raw.y, raw.z, raw.w};
        #pragma unroll
        for (int q = 0; q < 4; q++) {
            float lo, hi;
            unpack2(vals[q], lo, hi);
            s  += lo * att_s[h * 32 + i0 + q * 2] + hi * att_s[h * 32 + i0 + q * 2 + 1];
            dd += lo * att_d[h * 32 + i0 + q * 2] + hi * att_d[h * 32 + i0 + q * 2 + 1];
        }
    }
    a_s[t] = s * LOG2E; a_d[t] = dd * LOG2E;
}

__global__ __launch_bounds__(256) void attn_node1(
    const unsigned short* __restrict__ xp, const float* __restrict__ att_s,
    const float* __restrict__ att_d, float* __restrict__ a_s, float* __restrict__ a_d)
{
    int w = (blockIdx.x * 256 + threadIdx.x) >> 6;
    int lane = threadIdx.x & 63;
    if (w >= NN) return;
    ushort4 raw = ((const ushort4*)(xp + (size_t)w * 256))[lane];
    float4 a = ((const float4*)att_s)[lane];
    float4 b = ((const float4*)att_d)[lane];
    float v0 = bf2f(raw.x), v1 = bf2f(raw.y), v2 = bf2f(raw.z), v3 = bf2f(raw.w);
    float s  = v0 * a.x + v1 * a.y + v2 * a.z + v3 * a.w;
    float dd = v0 * b.x + v1 * b.y + v2 * b.z + v3 * b.w;
    #pragma unroll
    for (int off = 32; off; off >>= 1) {
        s  += __shfl_down(s, off);
        dd += __shfl_down(dd, off);
    }
    if (lane == 0) { a_s[w] = s * LOG2E; a_d[w] = dd * LOG2E; }
}

// ---------------- gather0 (wave per dst node), unroll x4, fused BN stats ------------
__global__ __launch_bounds__(256) void gather0(
    const int* __restrict__ adj, const int* __restrict__ rowptr,
    const unsigned short* __restrict__ xp, const float* __restrict__ a_s,
    const float* __restrict__ a_d, unsigned short* __restrict__ out0,
    float* __restrict__ bnsum, float* __restrict__ bnsq)
{
    __shared__ float ls[512];
    int tid = threadIdx.x;
    ls[tid] = 0.f; ls[tid + 256] = 0.f;
    __syncthreads();
    int w = (blockIdx.x * 256 + tid) >> 6;
    int lane = tid & 63;
    if (w < NN) {
        int h = lane >> 3;
        float ad = a_d[w * 8 + h];
        int p = rowptr[w], end = rowptr[w + 1];
        unsigned loff = (unsigned)lane * 8u;
        float ax0=0,ay0=0,az0=0,aw0=0, ax1=0,ay1=0,az1=0,aw1=0;
        float den = 0.f;
        for (; p + 4 <= end; p += 4) {
            int s0 = adj[p], s1 = adj[p+1], s2 = adj[p+2], s3 = adj[p+3];
            float e0 = a_s[s0 * 8 + h] + ad;
            float e1 = a_s[s1 * 8 + h] + ad;
            float e2 = a_s[s2 * 8 + h] + ad;
            float e3 = a_s[s3 * 8 + h] + ad;
            float w0 = __builtin_amdgcn_exp2f(fmaxf(e0, 0.2f * e0));
            float w1 = __builtin_amdgcn_exp2f(fmaxf(e1, 0.2f * e1));
            float w2 = __builtin_amdgcn_exp2f(fmaxf(e2, 0.2f * e2));
            float w3 = __builtin_amdgcn_exp2f(fmaxf(e3, 0.2f * e3));
            uint2 r0 = *(const uint2*)((const char*)xp + ((unsigned)s0 * 512u + loff));
            uint2 r1 = *(const uint2*)((const char*)xp + ((unsigned)s1 * 512u + loff));
            uint2 r2 = *(const uint2*)((const char*)xp + ((unsigned)s2 * 512u + loff));
            uint2 r3 = *(const uint2*)((const char*)xp + ((unsigned)s3 * 512u + loff));
            den += (w0 + w1) + (w2 + w3);
            float lo, hi;
            unpack2(r0.x, lo, hi); ax0 += w0 * lo; ay0 += w0 * hi;
            unpack2(r0.y, lo, hi); az0 += w0 * lo; aw0 += w0 * hi;
            unpack2(r1.x, lo, hi); ax1 += w1 * lo; ay1 += w1 * hi;
            unpack2(r1.y, lo, hi); az1 += w1 * lo; aw1 += w1 * hi;
            unpack2(r2.x, lo, hi); ax0 += w2 * lo; ay0 += w2 * hi;
            unpack2(r2.y, lo, hi); az0 += w2 * lo; aw0 += w2 * hi;
            unpack2(r3.x, lo, hi); ax1 += w3 * lo; ay1 += w3 * hi;
            unpack2(r3.y, lo, hi); az1 += w3 * lo; aw1 += w3 * hi;
        }
        for (; p < end; p++) {
            int s0 = adj[p];
            float e0 = a_s[s0 * 8 + h] + ad;
            float w0 = __builtin_amdgcn_exp2f(fmaxf(e0, 0.2f * e0));
            uint2 r0 = *(const uint2*)((const char*)xp + ((unsigned)s0 * 512u + loff));
            den += w0;
            float lo, hi;
            unpack2(r0.x, lo, hi); ax0 += w0 * lo; ay0 += w0 * hi;
            unpack2(r0.y, lo, hi); az0 += w0 * lo; aw0 += w0 * hi;
        }
        float inv = 1.f / (den + 1e-16f);
        float vx = (ax0 + ax1) * inv, vy = (ay0 + ay1) * inv;
        float vz = (az0 + az1) * inv, vw = (aw0 + aw1) * inv;
        ushort4 o;
        o.x = f2bf(vx); o.y = f2bf(vy); o.z = f2bf(vz); o.w = f2bf(vw);
        ((ushort4*)(out0 + (size_t)w * 256))[lane] = o;
        int c0 = lane * 4;
        atomicAdd(&ls[c0 + 0], vx); atomicAdd(&ls[256 + c0 + 0], vx * vx);
        atomicAdd(&ls[c0 + 1], vy); atomicAdd(&ls[256 + c0 + 1], vy * vy);
        atomicAdd(&ls[c0 + 2], vz); atomicAdd(&ls[256 + c0 + 2], vz * vz);
        atomicAdd(&ls[c0 + 3], vw); atomicAdd(&ls[256 + c0 + 3], vw * vw);
    }
    __syncthreads();
    atomicAdd(&bnsum[tid], ls[tid]);
    atomicAdd(&bnsq[tid], ls[tid + 256]);
}

// ---------------- BN coefficients ----------------
__global__ __launch_bounds__(256) void bn_coef(
    const float* __restrict__ bnsum, const float* __restrict__ bnsq,
    const float* __restrict__ gamma, const float* __restrict__ beta,
    float* __restrict__ scl, float* __restrict__ sft)
{
    int c = threadIdx.x;
    const float invN = 1.0f / (float)NN;
    float mu = bnsum[c] * invN;
    float var = bnsq[c] * invN - mu * mu;
    float s = rsqrtf(var + 1e-5f) * gamma[c];
    scl[c] = s;
    sft[c] = beta[c] - mu * s;
}

// ---------------- elementwise: h = elu(bn(out0)) + skip (in place on skip buf) ------
__global__ __launch_bounds__(256) void bn_elu(
    const unsigned short* __restrict__ out0, unsigned short* __restrict__ hb,
    const float* __restrict__ scl, const float* __restrict__ sft,
    const float* __restrict__ bskip)
{
    int i = blockIdx.x * 256 + threadIdx.x;   // one per 8 elems
    if (i >= MPAD * 256 / 8) return;
    int col0 = (i * 8) & 255;
    uint4 hv = ((const uint4*)out0)[i];
    uint4 sv = ((const uint4*)hb)[i];
    float4 c0 = *(const float4*)(scl + col0);
    float4 c1 = *(const float4*)(scl + col0 + 4);
    float4 f0 = *(const float4*)(sft + col0);
    float4 f1 = *(const float4*)(sft + col0 + 4);
    float4 k0 = *(const float4*)(bskip + col0);
    float4 k1 = *(const float4*)(bskip + col0 + 4);
    float bn[8], sk[8];
    unpack2(hv.x, bn[0], bn[1]); unpack2(hv.y, bn[2], bn[3]);
    unpack2(hv.z, bn[4], bn[5]); unpack2(hv.w, bn[6], bn[7]);
    unpack2(sv.x, sk[0], sk[1]); unpack2(sv.y, sk[2], sk[3]);
    unpack2(sv.z, sk[4], sk[5]); unpack2(sv.w, sk[6], sk[7]);
    float cc[8] = {c0.x,c0.y,c0.z,c0.w,c1.x,c1.y,c1.z,c1.w};
    float ff[8] = {f0.x,f0.y,f0.z,f0.w,f1.x,f1.y,f1.z,f1.w};
    float kk[8] = {k0.x,k0.y,k0.z,k0.w,k1.x,k1.y,k1.z,k1.w};
    float r[8];
    #pragma unroll
    for (int q = 0; q < 8; q++) {
        float b = bn[q] * cc[q] + ff[q];
        float el = b > 0.f ? b : (__expf(b) - 1.f);
        r[q] = el + sk[q] + kk[q];
    }
    uint4 o;
    o.x = pack2(r[0], r[1]); o.y = pack2(r[2], r[3]);
    o.z = pack2(r[4], r[5]); o.w = pack2(r[6], r[7]);
    ((uint4*)hb)[i] = o;
}

// ---------------- gather1 (1 head), unroll x4, +b1, f32 out ----------------
__global__ __launch_bounds__(256) void gather1(
    const int* __restrict__ adj, const int* __restrict__ rowptr,
    const unsigned short* __restrict__ xp, const float* __restrict__ a_s,
    const float* __restrict__ a_d, const float* __restrict__ b1,
    float* __restrict__ out)
{
    int w = (blockIdx.x * 256 + threadIdx.x) >> 6;
    int lane = threadIdx.x & 63;
    if (w >= NN) return;
    float ad = a_d[w];
    int p = rowptr[w], end = rowptr[w + 1];
    unsigned loff = (unsigned)lane * 8u;
    float ax0=0,ay0=0,az0=0,aw0=0, ax1=0,ay1=0,az1=0,aw1=0;
    float den = 0.f;
    for (; p + 4 <= end; p += 4) {
        int s0 = adj[p], s1 = adj[p+1], s2 = adj[p+2], s3 = adj[p+3];
        float e0 = a_s[s0] + ad;
        float e1 = a_s[s1] + ad;
        float e2 = a_s[s2] + ad;
        float e3 = a_s[s3] + ad;
        float w0 = __builtin_amdgcn_exp2f(fmaxf(e0, 0.2f * e0));
        float w1 = __builtin_amdgcn_exp2f(fmaxf(e1, 0.2f * e1));
        float w2 = __builtin_amdgcn_exp2f(fmaxf(e2, 0.2f * e2));
        float w3 = __builtin_amdgcn_exp2f(fmaxf(e3, 0.2f * e3));
        uint2 r0 = *(const uint2*)((const char*)xp + ((unsigned)s0 * 512u + loff));
        uint2 r1 = *(const uint2*)((const char*)xp + ((unsigned)s1 * 512u + loff));
        uint2 r2 = *(const uint2*)((const char*)xp + ((unsigned)s2 * 512u + loff));
        uint2 r3 = *(const uint2*)((const char*)xp + ((unsigned)s3 * 512u + loff));
        den += (w0 + w1) + (w2 + w3);
        float lo, hi;
        unpack2(r0.x, lo, hi); ax0 += w0 * lo; ay0 += w0 * hi;
        unpack2(r0.y, lo, hi); az0 += w0 * lo; aw0 += w0 * hi;
        unpack2(r1.x, lo, hi); ax1 += w1 * lo; ay1 += w1 * hi;
        unpack2(r1.y, lo, hi); az1 += w1 * lo; aw1 += w1 * hi;
        unpack2(r2.x, lo, hi); ax0 += w2 * lo; ay0 += w2 * hi;
        unpack2(r2.y, lo, hi); az0 += w2 * lo; aw0 += w2 * hi;
        unpack2(r3.x, lo, hi); ax1 += w3 * lo; ay1 += w3 * hi;
        unpack2(r3.y, lo, hi); az1 += w3 * lo; aw1 += w3 * hi;
    }
    for (; p < end; p++) {
        int s0 = adj[p];
        float e0 = a_s[s0] + ad;
        float w0 = __builtin_amdgcn_exp2f(fmaxf(e0, 0.2f * e0));
        uint2 r0 = *(const uint2*)((const char*)xp + ((unsigned)s0 * 512u + loff));
        den += w0;
        float lo, hi;
        unpack2(r0.x, lo, hi); ax0 += w0 * lo; ay0 += w0 * hi;
        unpack2(r0.y, lo, hi); az0 += w0 * lo; aw0 += w0 * hi;
    }
    float inv = 1.f / (den + 1e-16f);
    float4 b = ((const float4*)b1)[lane];
    float4 r = {(ax0 + ax1) * inv + b.x, (ay0 + ay1) * inv + b.y,
                (az0 + az1) * inv + b.z, (aw0 + aw1) * inv + b.w};
    ((float4*)(out + (size_t)w * 256))[lane] = r;
}

extern "C" void kernel_launch(void* const* d_in, const int* in_sizes, int n_in,
                              void* d_out, int out_size, void* d_ws, size_t ws_size,
                              hipStream_t stream)
{
    const float* x      = (const float*)d_in[0];
    const int*   ei     = (const int*)d_in[1];
    const float* W0     = (const float*)d_in[2];
    const float* att_s0 = (const float*)d_in[3];
    const float* att_d0 = (const float*)d_in[4];
    // b0 (d_in[5]) cancels under BatchNorm -> unused
    const float* gamma0 = (const float*)d_in[6];
    const float* beta0  = (const float*)d_in[7];
    const float* W_skip = (const float*)d_in[8];
    const float* b_skip = (const float*)d_in[9];
    const float* W1     = (const float*)d_in[10];
    const float* att_s1 = (const float*)d_in[11];
    const float* att_d1 = (const float*)d_in[12];
    const float* b1     = (const float*)d_in[13];
    float* out = (float*)d_out;

    // workspace layout
    char* p = (char*)d_ws;
    unsigned short* x_bf  = (unsigned short*)p; p += (size_t)MPAD * 128 * 2;
    unsigned short* xp_bf = (unsigned short*)p; p += (size_t)MPAD * 256 * 2;  // xp0 then xp1
    unsigned short* h_bf  = (unsigned short*)p; p += (size_t)MPAD * 256 * 2;  // skip, then h in place
    unsigned short* out0b = (unsigned short*)p; p += (size_t)MPAD * 256 * 2;
    unsigned short* Wtc   = (unsigned short*)p; p += (size_t)512 * 128 * 2;   // [W0t | Wst]
    unsigned short* W1t   = (unsigned short*)p; p += (size_t)256 * 256 * 2;
    float* a_s   = (float*)p; p += (size_t)NN * 8 * 4;
    float* a_d   = (float*)p; p += (size_t)NN * 8 * 4;
    float* bnsum = (float*)p; p += 256 * 4;
    float* bnsq  = (float*)p; p += 256 * 4;
    float* scl   = (float*)p; p += 256 * 4;
    float* sft   = (float*)p; p += 256 * 4;
    int* deg    = (int*)p; p += (size_t)NN * 4;
    int* rowptr = (int*)p; p += (size_t)(NN + 1) * 4;
    int* cursor = (int*)p; p += (size_t)NN * 4;
    int* adj    = (int*)p; p += (size_t)ET * 4;

    hipMemsetAsync(deg, 0, (size_t)NN * 4, stream);
    hipMemsetAsync(bnsum, 0, 512 * 4, stream);
    // deterministic pad rows for out0b (never written by gather0)
    hipMemsetAsync(out0b + (size_t)NN * 256, 0, (size_t)(MPAD - NN) * 256 * 2, stream);

    // converts
    conv_x<<<(MPAD * 128 / 4 + 255) / 256, 256, 0, stream>>>(x, x_bf);
    conv_wt<<<(128 * 256 + 255) / 256, 256, 0, stream>>>(W0, Wtc, 128);
    conv_wt<<<(128 * 256 + 255) / 256, 256, 0, stream>>>(W_skip, Wtc + 256 * 128, 128);
    conv_wt<<<(256 * 256 + 255) / 256, 256, 0, stream>>>(W1, W1t, 256);

    // CSR build
    csr_count<<<(ET + 255) / 256, 256, 0, stream>>>(ei, deg);
    exscan<<<1, 1024, 0, stream>>>(deg, rowptr, cursor);
    csr_fill<<<(ET + 255) / 256, 256, 0, stream>>>(ei, cursor, adj);

    // ---- layer 0: combined GEMM (xp | skip) ----
    dim3 gg0(MPAD / 128, 4);
    gemm_bf16<<<gg0, 256, 0, stream>>>(x_bf, Wtc, xp_bf, h_bf, 128);
    attn_node0<<<(NN * 8 + 255) / 256, 256, 0, stream>>>(xp_bf, att_s0, att_d0, a_s, a_d);
    gather0<<<(NN * 64 + 255) / 256, 256, 0, stream>>>(adj, rowptr, xp_bf, a_s, a_d,
                                                       out0b, bnsum, bnsq);

    // ---- BN + ELU + skip (elementwise, in place on h_bf) ----
    bn_coef<<<1, 256, 0, stream>>>(bnsum, bnsq, gamma0, beta0, scl, sft);
    bn_elu<<<(MPAD * 256 / 8 + 255) / 256, 256, 0, stream>>>(out0b, h_bf, scl, sft, b_skip);

    // ---- layer 1 ----
    dim3 gg1(MPAD / 128, 2);
    gemm_bf16<<<gg1, 256, 0, stream>>>(h_bf, W1t, xp_bf, xp_bf, 256);
    attn_node1<<<(NN * 64 + 255) / 256, 256, 0, stream>>>(xp_bf, att_s1, att_d1, a_s, a_d);
    gather1<<<(NN * 64 + 255) / 256, 256, 0, stream>>>(adj, rowptr, xp_bf, a_s, a_d, b1, out);
}

// Round 6
// 342.356 us; speedup vs baseline: 1.5496x; 1.5496x over previous
//
#include <hip/hip_runtime.h>
#include <hip/hip_bf16.h>

#define NN 40000
#define EE 640000
#define ET 680000   // EE + NN self loops
#define MPAD 40064  // 313 * 128
#define LOG2E 1.4426950408889634f

typedef __attribute__((ext_vector_type(8))) short short8;
typedef __attribute__((ext_vector_type(4))) float f32x4;

__device__ __forceinline__ float bf2f(unsigned u) {
    return __uint_as_float(u << 16);
}
__device__ __forceinline__ unsigned short f2bf(float f) {
    unsigned u = __float_as_uint(f);
    return (unsigned short)((u + 0x7FFFu + ((u >> 16) & 1u)) >> 16);
}
__device__ __forceinline__ unsigned pack2(float lo, float hi) {
    return ((unsigned)f2bf(lo)) | (((unsigned)f2bf(hi)) << 16);
}
__device__ __forceinline__ void unpack2(unsigned u, float& lo, float& hi) {
    lo = __uint_as_float(u << 16);
    hi = __uint_as_float(u & 0xffff0000u);
}

// ---------------- converts ----------------
__global__ __launch_bounds__(256) void conv_x(const float* __restrict__ x,
                                              unsigned short* __restrict__ xb)
{
    int i = blockIdx.x * 256 + threadIdx.x;          // one per 4 elems
    if (i >= MPAD * 128 / 4) return;
    int row = (i * 4) >> 7;
    ushort4 o;
    if (row < NN) {
        float4 v = ((const float4*)x)[i];
        o.x = f2bf(v.x); o.y = f2bf(v.y); o.z = f2bf(v.z); o.w = f2bf(v.w);
    } else { o.x = o.y = o.z = o.w = 0; }
    ((ushort4*)xb)[i] = o;
}

// W[K][256] f32 -> Wt[256][K] bf16
__global__ __launch_bounds__(256) void conv_wt(const float* __restrict__ W,
                                               unsigned short* __restrict__ Wt, int K)
{
    int i = blockIdx.x * 256 + threadIdx.x;
    if (i >= K * 256) return;
    int c = i / K, k = i - c * K;
    Wt[i] = f2bf(W[(size_t)k * 256 + c]);
}

// ---------------- MFMA GEMM: Cd[MPAD][256] = A[MPAD][K] @ Bt^T (dual output) ----------
__global__ __launch_bounds__(256) void gemm_bf16(
    const unsigned short* __restrict__ A, const unsigned short* __restrict__ Btc,
    unsigned short* __restrict__ C0, unsigned short* __restrict__ C1, int K)
{
    __shared__ unsigned short As[128 * 64];
    int tid = threadIdx.x;
    int rb = blockIdx.x * 128, cb = blockIdx.y * 128;
    int lane = tid & 63, wid = tid >> 6;
    int wm = (wid >> 1) * 64, wn = (wid & 1) * 64;
    int lr = lane & 15, lk = lane >> 4;
    f32x4 acc[4][4] = {};
    for (int kb = 0; kb < K; kb += 64) {
        #pragma unroll
        for (int i = 0; i < 4; i++) {
            int flat = tid + i * 256;
            int r = flat >> 3, c8 = flat & 7;
            int4 v = *(const int4*)(A + (size_t)(rb + r) * K + kb + c8 * 8);
            *(int4*)(&As[r * 64 + ((c8 ^ (r & 7)) * 8)]) = v;
        }
        __syncthreads();
        #pragma unroll
        for (int kk = 0; kk < 2; kk++) {
            int kbase = kb + kk * 32 + lk * 8;
            short8 bfr[4], afr[4];
            #pragma unroll
            for (int n = 0; n < 4; n++)
                bfr[n] = *(const short8*)(Btc + (size_t)(cb + wn + n * 16 + lr) * K + kbase);
            #pragma unroll
            for (int m = 0; m < 4; m++) {
                int row = wm + m * 16 + lr;
                int kchunk = kk * 4 + lk;
                afr[m] = *(const short8*)(&As[row * 64 + ((kchunk ^ (row & 7)) * 8)]);
            }
            #pragma unroll
            for (int m = 0; m < 4; m++)
                #pragma unroll
                for (int n = 0; n < 4; n++)
                    acc[m][n] = __builtin_amdgcn_mfma_f32_16x16x32_bf16(afr[m], bfr[n], acc[m][n], 0, 0, 0);
        }
        __syncthreads();
    }
    unsigned short* C = (cb < 256) ? C0 : C1;
    int cbase = cb & 255;
    #pragma unroll
    for (int m = 0; m < 4; m++)
        #pragma unroll
        for (int n = 0; n < 4; n++) {
            int col = cbase + wn + n * 16 + lr;
            #pragma unroll
            for (int j = 0; j < 4; j++) {
                int row = rb + wm + m * 16 + lk * 4 + j;
                C[(size_t)row * 256 + col] = f2bf(acc[m][n][j]);
            }
        }
}

// ---------------- CSR build (by dst) ----------------
__global__ __launch_bounds__(256) void csr_count(const int* __restrict__ ei, int* __restrict__ deg)
{
    int e = blockIdx.x * blockDim.x + threadIdx.x;
    if (e >= ET) return;
    int d = (e < EE) ? ei[EE + e] : (e - EE);
    atomicAdd(&deg[d], 1);
}

__global__ __launch_bounds__(1024) void exscan(
    const int* __restrict__ deg, int* __restrict__ rowptr, int* __restrict__ cursor)
{
    __shared__ int wsum[16];
    __shared__ int carry_s;
    int tid = threadIdx.x, lane = tid & 63, wid = tid >> 6;
    if (tid == 0) carry_s = 0;
    __syncthreads();
    for (int base = 0; base < NN; base += 1024) {
        int i = base + tid;
        int v = (i < NN) ? deg[i] : 0;
        int sc = v;
        #pragma unroll
        for (int off = 1; off < 64; off <<= 1) {
            int t = __shfl_up(sc, off);
            if (lane >= off) sc += t;
        }
        if (lane == 63) wsum[wid] = sc;
        __syncthreads();
        if (wid == 0 && lane < 16) {
            int t = wsum[lane];
            #pragma unroll
            for (int off = 1; off < 16; off <<= 1) {
                int u = __shfl_up(t, off);
                if (lane >= off) t += u;
            }
            wsum[lane] = t;
        }
        __syncthreads();
        int carry = carry_s;
        int wpre = wid ? wsum[wid - 1] : 0;
        int excl = carry + wpre + sc - v;
        if (i < NN) { rowptr[i] = excl; cursor[i] = excl; }
        __syncthreads();
        if (tid == 0) carry_s = carry + wsum[15];
    }
    if (tid == 0) rowptr[NN] = carry_s;
}

__global__ __launch_bounds__(256) void csr_fill(
    const int* __restrict__ ei, int* __restrict__ cursor, int* __restrict__ adj)
{
    int e = blockIdx.x * blockDim.x + threadIdx.x;
    if (e >= ET) return;
    int s, d;
    if (e < EE) { s = ei[e]; d = ei[EE + e]; } else { s = d = e - EE; }
    int pos = atomicAdd(&cursor[d], 1);
    adj[pos] = s;
}

// ---------------- attention logits (pre-scaled by log2(e)) ----------------
__global__ __launch_bounds__(256) void attn_node0(
    const unsigned short* __restrict__ xp, const float* __restrict__ att_s,
    const float* __restrict__ att_d, float* __restrict__ a_s, float* __restrict__ a_d)
{
    int t = blockIdx.x * 256 + threadIdx.x;
    if (t >= NN * 8) return;
    int n = t >> 3, h = t & 7;
    const unsigned short* p = xp + (size_t)n * 256 + h * 32;
    float s = 0.f, dd = 0.f;
    #pragma unroll
    for (int i0 = 0; i0 < 32; i0 += 8) {
        uint4 raw = *(const uint4*)(p + i0);
        unsigned vals[4] = {raw.x, raw.y, raw.z, raw.w};
        #pragma unroll
        for (int q = 0; q < 4; q++) {
            float lo, hi;
            unpack2(vals[q], lo, hi);
            s  += lo * att_s[h * 32 + i0 + q * 2] + hi * att_s[h * 32 + i0 + q * 2 + 1];
            dd += lo * att_d[h * 32 + i0 + q * 2] + hi * att_d[h * 32 + i0 + q * 2 + 1];
        }
    }
    a_s[t] = s * LOG2E; a_d[t] = dd * LOG2E;
}

__global__ __launch_bounds__(256) void attn_node1(
    const unsigned short* __restrict__ xp, const float* __restrict__ att_s,
    const float* __restrict__ att_d, float* __restrict__ a_s, float* __restrict__ a_d)
{
    int w = (blockIdx.x * 256 + threadIdx.x) >> 6;
    int lane = threadIdx.x & 63;
    if (w >= NN) return;
    ushort4 raw = ((const ushort4*)(xp + (size_t)w * 256))[lane];
    float4 a = ((const float4*)att_s)[lane];
    float4 b = ((const float4*)att_d)[lane];
    float v0 = bf2f(raw.x), v1 = bf2f(raw.y), v2 = bf2f(raw.z), v3 = bf2f(raw.w);
    float s  = v0 * a.x + v1 * a.y + v2 * a.z + v3 * a.w;
    float dd = v0 * b.x + v1 * b.y + v2 * b.z + v3 * b.w;
    #pragma unroll
    for (int off = 32; off; off >>= 1) {
        s  += __shfl_down(s, off);
        dd += __shfl_down(dd, off);
    }
    if (lane == 0) { a_s[w] = s * LOG2E; a_d[w] = dd * LOG2E; }
}

// ---------------- gather0 (wave per dst node), unroll x2 (R4-proven body) ----------
__global__ __launch_bounds__(256) void gather0(
    const int* __restrict__ adj, const int* __restrict__ rowptr,
    const unsigned short* __restrict__ xp, const float* __restrict__ a_s,
    const float* __restrict__ a_d, unsigned short* __restrict__ out0)
{
    int w = (blockIdx.x * 256 + threadIdx.x) >> 6;
    int lane = threadIdx.x & 63;
    if (w >= NN) return;
    int h = lane >> 3;
    float ad = a_d[w * 8 + h];
    int p = rowptr[w], end = rowptr[w + 1];
    unsigned loff = (unsigned)lane * 8u;
    float ax0=0,ay0=0,az0=0,aw0=0, ax1=0,ay1=0,az1=0,aw1=0;
    float den0 = 0.f, den1 = 0.f;
    for (; p + 2 <= end; p += 2) {
        int s0 = adj[p], s1 = adj[p + 1];
        float e0 = a_s[s0 * 8 + h] + ad;
        float e1 = a_s[s1 * 8 + h] + ad;
        float w0 = __builtin_amdgcn_exp2f(fmaxf(e0, 0.2f * e0));
        float w1 = __builtin_amdgcn_exp2f(fmaxf(e1, 0.2f * e1));
        uint2 r0 = *(const uint2*)((const char*)xp + ((unsigned)s0 * 512u + loff));
        uint2 r1 = *(const uint2*)((const char*)xp + ((unsigned)s1 * 512u + loff));
        den0 += w0; den1 += w1;
        float lo, hi;
        unpack2(r0.x, lo, hi); ax0 += w0 * lo; ay0 += w0 * hi;
        unpack2(r0.y, lo, hi); az0 += w0 * lo; aw0 += w0 * hi;
        unpack2(r1.x, lo, hi); ax1 += w1 * lo; ay1 += w1 * hi;
        unpack2(r1.y, lo, hi); az1 += w1 * lo; aw1 += w1 * hi;
    }
    if (p < end) {
        int s0 = adj[p];
        float e0 = a_s[s0 * 8 + h] + ad;
        float w0 = __builtin_amdgcn_exp2f(fmaxf(e0, 0.2f * e0));
        uint2 r0 = *(const uint2*)((const char*)xp + ((unsigned)s0 * 512u + loff));
        den0 += w0;
        float lo, hi;
        unpack2(r0.x, lo, hi); ax0 += w0 * lo; ay0 += w0 * hi;
        unpack2(r0.y, lo, hi); az0 += w0 * lo; aw0 += w0 * hi;
    }
    float inv = 1.f / (den0 + den1 + 1e-16f);
    ushort4 o;
    o.x = f2bf((ax0 + ax1) * inv); o.y = f2bf((ay0 + ay1) * inv);
    o.z = f2bf((az0 + az1) * inv); o.w = f2bf((aw0 + aw1) * inv);
    ((ushort4*)(out0 + (size_t)w * 256))[lane] = o;
}

// ---------------- BN column stats (bf16 input, standalone — R4-proven) ----------------
__global__ __launch_bounds__(256) void bn_stats(
    const unsigned short* __restrict__ H, float* __restrict__ bnsum, float* __restrict__ bnsq)
{
    int c = threadIdx.x;
    int r0 = blockIdx.x * 64;
    float s = 0.f, sq = 0.f;
    for (int r = r0; r < r0 + 64; r++) {
        float v = bf2f(H[(size_t)r * 256 + c]);
        s += v; sq += v * v;
    }
    atomicAdd(&bnsum[c], s);
    atomicAdd(&bnsq[c], sq);
}

// ---------------- BN coefficients ----------------
__global__ __launch_bounds__(256) void bn_coef(
    const float* __restrict__ bnsum, const float* __restrict__ bnsq,
    const float* __restrict__ gamma, const float* __restrict__ beta,
    float* __restrict__ scl, float* __restrict__ sft)
{
    int c = threadIdx.x;
    const float invN = 1.0f / (float)NN;
    float mu = bnsum[c] * invN;
    float var = bnsq[c] * invN - mu * mu;
    float s = rsqrtf(var + 1e-5f) * gamma[c];
    scl[c] = s;
    sft[c] = beta[c] - mu * s;
}

// ---------------- elementwise: h = elu(bn(out0)) + skip (in place on skip buf) ------
__global__ __launch_bounds__(256) void bn_elu(
    const unsigned short* __restrict__ out0, unsigned short* __restrict__ hb,
    const float* __restrict__ scl, const float* __restrict__ sft,
    const float* __restrict__ bskip)
{
    int i = blockIdx.x * 256 + threadIdx.x;   // one per 8 elems
    if (i >= MPAD * 256 / 8) return;
    int col0 = (i * 8) & 255;
    uint4 hv = ((const uint4*)out0)[i];
    uint4 sv = ((const uint4*)hb)[i];
    float4 c0 = *(const float4*)(scl + col0);
    float4 c1 = *(const float4*)(scl + col0 + 4);
    float4 f0 = *(const float4*)(sft + col0);
    float4 f1 = *(const float4*)(sft + col0 + 4);
    float4 k0 = *(const float4*)(bskip + col0);
    float4 k1 = *(const float4*)(bskip + col0 + 4);
    float bn[8], sk[8];
    unpack2(hv.x, bn[0], bn[1]); unpack2(hv.y, bn[2], bn[3]);
    unpack2(hv.z, bn[4], bn[5]); unpack2(hv.w, bn[6], bn[7]);
    unpack2(sv.x, sk[0], sk[1]); unpack2(sv.y, sk[2], sk[3]);
    unpack2(sv.z, sk[4], sk[5]); unpack2(sv.w, sk[6], sk[7]);
    float cc[8] = {c0.x,c0.y,c0.z,c0.w,c1.x,c1.y,c1.z,c1.w};
    float ff[8] = {f0.x,f0.y,f0.z,f0.w,f1.x,f1.y,f1.z,f1.w};
    float kk[8] = {k0.x,k0.y,k0.z,k0.w,k1.x,k1.y,k1.z,k1.w};
    float r[8];
    #pragma unroll
    for (int q = 0; q < 8; q++) {
        float b = bn[q] * cc[q] + ff[q];
        float el = b > 0.f ? b : (__expf(b) - 1.f);
        r[q] = el + sk[q] + kk[q];
    }
    uint4 o;
    o.x = pack2(r[0], r[1]); o.y = pack2(r[2], r[3]);
    o.z = pack2(r[4], r[5]); o.w = pack2(r[6], r[7]);
    ((uint4*)hb)[i] = o;
}

// ---------------- gather1 (1 head), unroll x2, +b1, f32 out ----------------
__global__ __launch_bounds__(256) void gather1(
    const int* __restrict__ adj, const int* __restrict__ rowptr,
    const unsigned short* __restrict__ xp, const float* __restrict__ a_s,
    const float* __restrict__ a_d, const float* __restrict__ b1,
    float* __restrict__ out)
{
    int w = (blockIdx.x * 256 + threadIdx.x) >> 6;
    int lane = threadIdx.x & 63;
    if (w >= NN) return;
    float ad = a_d[w];
    int p = rowptr[w], end = rowptr[w + 1];
    unsigned loff = (unsigned)lane * 8u;
    float ax0=0,ay0=0,az0=0,aw0=0, ax1=0,ay1=0,az1=0,aw1=0;
    float den0 = 0.f, den1 = 0.f;
    for (; p + 2 <= end; p += 2) {
        int s0 = adj[p], s1 = adj[p + 1];
        float e0 = a_s[s0] + ad;
        float e1 = a_s[s1] + ad;
        float w0 = __builtin_amdgcn_exp2f(fmaxf(e0, 0.2f * e0));
        float w1 = __builtin_amdgcn_exp2f(fmaxf(e1, 0.2f * e1));
        uint2 r0 = *(const uint2*)((const char*)xp + ((unsigned)s0 * 512u + loff));
        uint2 r1 = *(const uint2*)((const char*)xp + ((unsigned)s1 * 512u + loff));
        den0 += w0; den1 += w1;
        float lo, hi;
        unpack2(r0.x, lo, hi); ax0 += w0 * lo; ay0 += w0 * hi;
        unpack2(r0.y, lo, hi); az0 += w0 * lo; aw0 += w0 * hi;
        unpack2(r1.x, lo, hi); ax1 += w1 * lo; ay1 += w1 * hi;
        unpack2(r1.y, lo, hi); az1 += w1 * lo; aw1 += w1 * hi;
    }
    if (p < end) {
        int s0 = adj[p];
        float e0 = a_s[s0] + ad;
        float w0 = __builtin_amdgcn_exp2f(fmaxf(e0, 0.2f * e0));
        uint2 r0 = *(const uint2*)((const char*)xp + ((unsigned)s0 * 512u + loff));
        den0 += w0;
        float lo, hi;
        unpack2(r0.x, lo, hi); ax0 += w0 * lo; ay0 += w0 * hi;
        unpack2(r0.y, lo, hi); az0 += w0 * lo; aw0 += w0 * hi;
    }
    float inv = 1.f / (den0 + den1 + 1e-16f);
    float4 b = ((const float4*)b1)[lane];
    float4 r = {(ax0 + ax1) * inv + b.x, (ay0 + ay1) * inv + b.y,
                (az0 + az1) * inv + b.z, (aw0 + aw1) * inv + b.w};
    ((float4*)(out + (size_t)w * 256))[lane] = r;
}

extern "C" void kernel_launch(void* const* d_in, const int* in_sizes, int n_in,
                              void* d_out, int out_size, void* d_ws, size_t ws_size,
                              hipStream_t stream)
{
    const float* x      = (const float*)d_in[0];
    const int*   ei     = (const int*)d_in[1];
    const float* W0     = (const float*)d_in[2];
    const float* att_s0 = (const float*)d_in[3];
    const float* att_d0 = (const float*)d_in[4];
    // b0 (d_in[5]) cancels under BatchNorm -> unused
    const float* gamma0 = (const float*)d_in[6];
    const float* beta0  = (const float*)d_in[7];
    const float* W_skip = (const float*)d_in[8];
    const float* b_skip = (const float*)d_in[9];
    const float* W1     = (const float*)d_in[10];
    const float* att_s1 = (const float*)d_in[11];
    const float* att_d1 = (const float*)d_in[12];
    const float* b1     = (const float*)d_in[13];
    float* out = (float*)d_out;

    // workspace layout
    char* p = (char*)d_ws;
    unsigned short* x_bf  = (unsigned short*)p; p += (size_t)MPAD * 128 * 2;
    unsigned short* xp_bf = (unsigned short*)p; p += (size_t)MPAD * 256 * 2;  // xp0 then xp1
    unsigned short* h_bf  = (unsigned short*)p; p += (size_t)MPAD * 256 * 2;  // skip, then h in place
    unsigned short* out0b = (unsigned short*)p; p += (size_t)MPAD * 256 * 2;
    unsigned short* Wtc   = (unsigned short*)p; p += (size_t)512 * 128 * 2;   // [W0t | Wst]
    unsigned short* W1t   = (unsigned short*)p; p += (size_t)256 * 256 * 2;
    float* a_s   = (float*)p; p += (size_t)NN * 8 * 4;
    float* a_d   = (float*)p; p += (size_t)NN * 8 * 4;
    float* bnsum = (float*)p; p += 256 * 4;
    float* bnsq  = (float*)p; p += 256 * 4;
    float* scl   = (float*)p; p += 256 * 4;
    float* sft   = (float*)p; p += 256 * 4;
    int* deg    = (int*)p; p += (size_t)NN * 4;
    int* rowptr = (int*)p; p += (size_t)(NN + 1) * 4;
    int* cursor = (int*)p; p += (size_t)NN * 4;
    int* adj    = (int*)p; p += (size_t)ET * 4;

    hipMemsetAsync(deg, 0, (size_t)NN * 4, stream);
    hipMemsetAsync(bnsum, 0, 512 * 4, stream);
    // deterministic pad rows for out0b (never written by gather0)
    hipMemsetAsync(out0b + (size_t)NN * 256, 0, (size_t)(MPAD - NN) * 256 * 2, stream);

    // converts
    conv_x<<<(MPAD * 128 / 4 + 255) / 256, 256, 0, stream>>>(x, x_bf);
    conv_wt<<<(128 * 256 + 255) / 256, 256, 0, stream>>>(W0, Wtc, 128);
    conv_wt<<<(128 * 256 + 255) / 256, 256, 0, stream>>>(W_skip, Wtc + 256 * 128, 128);
    conv_wt<<<(256 * 256 + 255) / 256, 256, 0, stream>>>(W1, W1t, 256);

    // CSR build
    csr_count<<<(ET + 255) / 256, 256, 0, stream>>>(ei, deg);
    exscan<<<1, 1024, 0, stream>>>(deg, rowptr, cursor);
    csr_fill<<<(ET + 255) / 256, 256, 0, stream>>>(ei, cursor, adj);

    // ---- layer 0: combined GEMM (xp | skip) ----
    dim3 gg0(MPAD / 128, 4);
    gemm_bf16<<<gg0, 256, 0, stream>>>(x_bf, Wtc, xp_bf, h_bf, 128);
    attn_node0<<<(NN * 8 + 255) / 256, 256, 0, stream>>>(xp_bf, att_s0, att_d0, a_s, a_d);
    gather0<<<(NN * 64 + 255) / 256, 256, 0, stream>>>(adj, rowptr, xp_bf, a_s, a_d, out0b);

    // ---- BN + ELU + skip (elementwise, in place on h_bf) ----
    bn_stats<<<NN / 64, 256, 0, stream>>>(out0b, bnsum, bnsq);
    bn_coef<<<1, 256, 0, stream>>>(bnsum, bnsq, gamma0, beta0, scl, sft);
    bn_elu<<<(MPAD * 256 / 8 + 255) / 256, 256, 0, stream>>>(out0b, h_bf, scl, sft, b_skip);

    // ---- layer 1 ----
    dim3 gg1(MPAD / 128, 2);
    gemm_bf16<<<gg1, 256, 0, stream>>>(h_bf, W1t, xp_bf, xp_bf, 256);
    attn_node1<<<(NN * 64 + 255) / 256, 256, 0, stream>>>(xp_bf, att_s1, att_d1, a_s, a_d);
    gather1<<<(NN * 64 + 255) / 256, 256, 0, stream>>>(adj, rowptr, xp_bf, a_s, a_d, b1, out);
}

// Round 7
// 326.909 us; speedup vs baseline: 1.6228x; 1.0473x over previous
//
#include <hip/hip_runtime.h>
#include <hip/hip_bf16.h>

#define NN 40000
#define EE 640000
#define ET 680000   // EE + NN self loops
#define MPAD 40064  // 313 * 128
#define LOG2E 1.4426950408889634f

typedef __attribute__((ext_vector_type(8))) short short8;
typedef __attribute__((ext_vector_type(4))) float f32x4;

__device__ __forceinline__ float bf2f(unsigned u) {
    return __uint_as_float(u << 16);
}
__device__ __forceinline__ unsigned short f2bf(float f) {
    unsigned u = __float_as_uint(f);
    return (unsigned short)((u + 0x7FFFu + ((u >> 16) & 1u)) >> 16);
}
__device__ __forceinline__ unsigned pack2(float lo, float hi) {
    return ((unsigned)f2bf(lo)) | (((unsigned)f2bf(hi)) << 16);
}
__device__ __forceinline__ void unpack2(unsigned u, float& lo, float& hi) {
    lo = __uint_as_float(u << 16);
    hi = __uint_as_float(u & 0xffff0000u);
}

// ---------------- converts ----------------
__global__ __launch_bounds__(256) void conv_x(const float* __restrict__ x,
                                              unsigned short* __restrict__ xb)
{
    int i = blockIdx.x * 256 + threadIdx.x;          // one per 4 elems
    if (i >= MPAD * 128 / 4) return;
    int row = (i * 4) >> 7;
    ushort4 o;
    if (row < NN) {
        float4 v = ((const float4*)x)[i];
        o.x = f2bf(v.x); o.y = f2bf(v.y); o.z = f2bf(v.z); o.w = f2bf(v.w);
    } else { o.x = o.y = o.z = o.w = 0; }
    ((ushort4*)xb)[i] = o;
}

// W[K][256] f32 -> Wt[256][K] bf16
__global__ __launch_bounds__(256) void conv_wt(const float* __restrict__ W,
                                               unsigned short* __restrict__ Wt, int K)
{
    int i = blockIdx.x * 256 + threadIdx.x;
    if (i >= K * 256) return;
    int c = i / K, k = i - c * K;
    Wt[i] = f2bf(W[(size_t)k * 256 + c]);
}

// ---------------- MFMA GEMM: Cd[MPAD][256] = A[MPAD][K] @ Bt^T (dual output) ----------
__global__ __launch_bounds__(256) void gemm_bf16(
    const unsigned short* __restrict__ A, const unsigned short* __restrict__ Btc,
    unsigned short* __restrict__ C0, unsigned short* __restrict__ C1, int K)
{
    __shared__ unsigned short As[128 * 64];
    int tid = threadIdx.x;
    int rb = blockIdx.x * 128, cb = blockIdx.y * 128;
    int lane = tid & 63, wid = tid >> 6;
    int wm = (wid >> 1) * 64, wn = (wid & 1) * 64;
    int lr = lane & 15, lk = lane >> 4;
    f32x4 acc[4][4] = {};
    for (int kb = 0; kb < K; kb += 64) {
        #pragma unroll
        for (int i = 0; i < 4; i++) {
            int flat = tid + i * 256;
            int r = flat >> 3, c8 = flat & 7;
            int4 v = *(const int4*)(A + (size_t)(rb + r) * K + kb + c8 * 8);
            *(int4*)(&As[r * 64 + ((c8 ^ (r & 7)) * 8)]) = v;
        }
        __syncthreads();
        #pragma unroll
        for (int kk = 0; kk < 2; kk++) {
            int kbase = kb + kk * 32 + lk * 8;
            short8 bfr[4], afr[4];
            #pragma unroll
            for (int n = 0; n < 4; n++)
                bfr[n] = *(const short8*)(Btc + (size_t)(cb + wn + n * 16 + lr) * K + kbase);
            #pragma unroll
            for (int m = 0; m < 4; m++) {
                int row = wm + m * 16 + lr;
                int kchunk = kk * 4 + lk;
                afr[m] = *(const short8*)(&As[row * 64 + ((kchunk ^ (row & 7)) * 8)]);
            }
            #pragma unroll
            for (int m = 0; m < 4; m++)
                #pragma unroll
                for (int n = 0; n < 4; n++)
                    acc[m][n] = __builtin_amdgcn_mfma_f32_16x16x32_bf16(afr[m], bfr[n], acc[m][n], 0, 0, 0);
        }
        __syncthreads();
    }
    unsigned short* C = (cb < 256) ? C0 : C1;
    int cbase = cb & 255;
    #pragma unroll
    for (int m = 0; m < 4; m++)
        #pragma unroll
        for (int n = 0; n < 4; n++) {
            int col = cbase + wn + n * 16 + lr;
            #pragma unroll
            for (int j = 0; j < 4; j++) {
                int row = rb + wm + m * 16 + lk * 4 + j;
                C[(size_t)row * 256 + col] = f2bf(acc[m][n][j]);
            }
        }
}

// ---------------- CSR build (by dst) ----------------
__global__ __launch_bounds__(256) void csr_count(const int* __restrict__ ei, int* __restrict__ deg)
{
    int e = blockIdx.x * blockDim.x + threadIdx.x;
    if (e >= ET) return;
    int d = (e < EE) ? ei[EE + e] : (e - EE);
    atomicAdd(&deg[d], 1);
}

__global__ __launch_bounds__(1024) void exscan(
    const int* __restrict__ deg, int* __restrict__ rowptr, int* __restrict__ cursor)
{
    __shared__ int wsum[16];
    __shared__ int carry_s;
    int tid = threadIdx.x, lane = tid & 63, wid = tid >> 6;
    if (tid == 0) carry_s = 0;
    __syncthreads();
    for (int base = 0; base < NN; base += 1024) {
        int i = base + tid;
        int v = (i < NN) ? deg[i] : 0;
        int sc = v;
        #pragma unroll
        for (int off = 1; off < 64; off <<= 1) {
            int t = __shfl_up(sc, off);
            if (lane >= off) sc += t;
        }
        if (lane == 63) wsum[wid] = sc;
        __syncthreads();
        if (wid == 0 && lane < 16) {
            int t = wsum[lane];
            #pragma unroll
            for (int off = 1; off < 16; off <<= 1) {
                int u = __shfl_up(t, off);
                if (lane >= off) t += u;
            }
            wsum[lane] = t;
        }
        __syncthreads();
        int carry = carry_s;
        int wpre = wid ? wsum[wid - 1] : 0;
        int excl = carry + wpre + sc - v;
        if (i < NN) { rowptr[i] = excl; cursor[i] = excl; }
        __syncthreads();
        if (tid == 0) carry_s = carry + wsum[15];
    }
    if (tid == 0) rowptr[NN] = carry_s;
}

__global__ __launch_bounds__(256) void csr_fill(
    const int* __restrict__ ei, int* __restrict__ cursor, int* __restrict__ adj)
{
    int e = blockIdx.x * blockDim.x + threadIdx.x;
    if (e >= ET) return;
    int s, d;
    if (e < EE) { s = ei[e]; d = ei[EE + e]; } else { s = d = e - EE; }
    int pos = atomicAdd(&cursor[d], 1);
    adj[pos] = s;
}

// ---------------- attention logits (pre-scaled by log2(e)) ----------------
__global__ __launch_bounds__(256) void attn_node0(
    const unsigned short* __restrict__ xp, const float* __restrict__ att_s,
    const float* __restrict__ att_d, float* __restrict__ a_s, float* __restrict__ a_d)
{
    int t = blockIdx.x * 256 + threadIdx.x;
    if (t >= NN * 8) return;
    int n = t >> 3, h = t & 7;
    const unsigned short* p = xp + (size_t)n * 256 + h * 32;
    float s = 0.f, dd = 0.f;
    #pragma unroll
    for (int i0 = 0; i0 < 32; i0 += 8) {
        uint4 raw = *(const uint4*)(p + i0);
        unsigned vals[4] = {raw.x, raw.y, raw.z, raw.w};
        #pragma unroll
        for (int q = 0; q < 4; q++) {
            float lo, hi;
            unpack2(vals[q], lo, hi);
            s  += lo * att_s[h * 32 + i0 + q * 2] + hi * att_s[h * 32 + i0 + q * 2 + 1];
            dd += lo * att_d[h * 32 + i0 + q * 2] + hi * att_d[h * 32 + i0 + q * 2 + 1];
        }
    }
    a_s[t] = s * LOG2E; a_d[t] = dd * LOG2E;
}

__global__ __launch_bounds__(256) void attn_node1(
    const unsigned short* __restrict__ xp, const float* __restrict__ att_s,
    const float* __restrict__ att_d, float* __restrict__ a_s, float* __restrict__ a_d)
{
    int w = (blockIdx.x * 256 + threadIdx.x) >> 6;
    int lane = threadIdx.x & 63;
    if (w >= NN) return;
    ushort4 raw = ((const ushort4*)(xp + (size_t)w * 256))[lane];
    float4 a = ((const float4*)att_s)[lane];
    float4 b = ((const float4*)att_d)[lane];
    float v0 = bf2f(raw.x), v1 = bf2f(raw.y), v2 = bf2f(raw.z), v3 = bf2f(raw.w);
    float s  = v0 * a.x + v1 * a.y + v2 * a.z + v3 * a.w;
    float dd = v0 * b.x + v1 * b.y + v2 * b.z + v3 * b.w;
    #pragma unroll
    for (int off = 32; off; off >>= 1) {
        s  += __shfl_down(s, off);
        dd += __shfl_down(dd, off);
    }
    if (lane == 0) { a_s[w] = s * LOG2E; a_d[w] = dd * LOG2E; }
}

// ---------------- gather0: half-wave edges, 8 ch/lane, 4 edges in flight ------------
// lanes 0-31 = edge stream A, lanes 32-63 = edge stream B; each lane: 16B (8 ch).
__global__ __launch_bounds__(256) void gather0(
    const int* __restrict__ adj, const int* __restrict__ rowptr,
    const unsigned short* __restrict__ xp, const float* __restrict__ a_s,
    const float* __restrict__ a_d, unsigned short* __restrict__ out0)
{
    int w = (blockIdx.x * 256 + threadIdx.x) >> 6;
    int lane = threadIdx.x & 63;
    if (w >= NN) return;
    int hl = lane & 31;               // half-lane
    int hw = lane >> 5;               // which half-wave
    int h = hl >> 2;                  // head = (8*hl)/32
    float ad = a_d[w * 8 + h];
    int p = rowptr[w], end = rowptr[w + 1];
    unsigned loff = (unsigned)hl * 16u;
    float a0=0,a1=0,a2=0,a3=0,a4=0,a5=0,a6=0,a7=0;
    float b0=0,b1=0,b2=0,b3=0,b4=0,b5=0,b6=0,b7=0;
    float den0 = 0.f, den1 = 0.f;
    for (; p + 4 <= end; p += 4) {
        int sA = adj[p + hw];          // half A: edge p,   half B: edge p+1
        int sB = adj[p + 2 + hw];      // half A: edge p+2, half B: edge p+3
        float eA = a_s[sA * 8 + h] + ad;
        float eB = a_s[sB * 8 + h] + ad;
        float wA = __builtin_amdgcn_exp2f(fmaxf(eA, 0.2f * eA));
        float wB = __builtin_amdgcn_exp2f(fmaxf(eB, 0.2f * eB));
        uint4 rA = *(const uint4*)((const char*)xp + ((unsigned)sA * 512u + loff));
        uint4 rB = *(const uint4*)((const char*)xp + ((unsigned)sB * 512u + loff));
        den0 += wA; den1 += wB;
        float lo, hi;
        unpack2(rA.x, lo, hi); a0 += wA * lo; a1 += wA * hi;
        unpack2(rA.y, lo, hi); a2 += wA * lo; a3 += wA * hi;
        unpack2(rA.z, lo, hi); a4 += wA * lo; a5 += wA * hi;
        unpack2(rA.w, lo, hi); a6 += wA * lo; a7 += wA * hi;
        unpack2(rB.x, lo, hi); b0 += wB * lo; b1 += wB * hi;
        unpack2(rB.y, lo, hi); b2 += wB * lo; b3 += wB * hi;
        unpack2(rB.z, lo, hi); b4 += wB * lo; b5 += wB * hi;
        unpack2(rB.w, lo, hi); b6 += wB * lo; b7 += wB * hi;
    }
    for (; p + 2 <= end; p += 2) {
        int sA = adj[p + hw];
        float eA = a_s[sA * 8 + h] + ad;
        float wA = __builtin_amdgcn_exp2f(fmaxf(eA, 0.2f * eA));
        uint4 rA = *(const uint4*)((const char*)xp + ((unsigned)sA * 512u + loff));
        den0 += wA;
        float lo, hi;
        unpack2(rA.x, lo, hi); a0 += wA * lo; a1 += wA * hi;
        unpack2(rA.y, lo, hi); a2 += wA * lo; a3 += wA * hi;
        unpack2(rA.z, lo, hi); a4 += wA * lo; a5 += wA * hi;
        unpack2(rA.w, lo, hi); a6 += wA * lo; a7 += wA * hi;
    }
    if (p < end) {                     // single tail edge: half A only
        int sA = adj[p];
        float eA = a_s[sA * 8 + h] + ad;
        float wA = hw ? 0.f : __builtin_amdgcn_exp2f(fmaxf(eA, 0.2f * eA));
        uint4 rA = *(const uint4*)((const char*)xp + ((unsigned)sA * 512u + loff));
        den0 += wA;
        float lo, hi;
        unpack2(rA.x, lo, hi); a0 += wA * lo; a1 += wA * hi;
        unpack2(rA.y, lo, hi); a2 += wA * lo; a3 += wA * hi;
        unpack2(rA.z, lo, hi); a4 += wA * lo; a5 += wA * hi;
        unpack2(rA.w, lo, hi); a6 += wA * lo; a7 += wA * hi;
    }
    a0 += b0; a1 += b1; a2 += b2; a3 += b3;
    a4 += b4; a5 += b5; a6 += b6; a7 += b7;
    float den = den0 + den1;
    den += __shfl_xor(den, 32);
    a0 += __shfl_xor(a0, 32); a1 += __shfl_xor(a1, 32);
    a2 += __shfl_xor(a2, 32); a3 += __shfl_xor(a3, 32);
    a4 += __shfl_xor(a4, 32); a5 += __shfl_xor(a5, 32);
    a6 += __shfl_xor(a6, 32); a7 += __shfl_xor(a7, 32);
    if (hw == 0) {
        float inv = 1.f / (den + 1e-16f);
        uint4 o;
        o.x = pack2(a0 * inv, a1 * inv);
        o.y = pack2(a2 * inv, a3 * inv);
        o.z = pack2(a4 * inv, a5 * inv);
        o.w = pack2(a6 * inv, a7 * inv);
        *(uint4*)((char*)out0 + ((size_t)w * 512u + loff)) = o;
    }
}

// ---------------- BN column stats (bf16 input, standalone) ----------------
__global__ __launch_bounds__(256) void bn_stats(
    const unsigned short* __restrict__ H, float* __restrict__ bnsum, float* __restrict__ bnsq)
{
    int c = threadIdx.x;
    int r0 = blockIdx.x * 64;
    float s = 0.f, sq = 0.f;
    for (int r = r0; r < r0 + 64; r++) {
        float v = bf2f(H[(size_t)r * 256 + c]);
        s += v; sq += v * v;
    }
    atomicAdd(&bnsum[c], s);
    atomicAdd(&bnsq[c], sq);
}

// ---------------- BN coefficients ----------------
__global__ __launch_bounds__(256) void bn_coef(
    const float* __restrict__ bnsum, const float* __restrict__ bnsq,
    const float* __restrict__ gamma, const float* __restrict__ beta,
    float* __restrict__ scl, float* __restrict__ sft)
{
    int c = threadIdx.x;
    const float invN = 1.0f / (float)NN;
    float mu = bnsum[c] * invN;
    float var = bnsq[c] * invN - mu * mu;
    float s = rsqrtf(var + 1e-5f) * gamma[c];
    scl[c] = s;
    sft[c] = beta[c] - mu * s;
}

// ---------------- elementwise: h = elu(bn(out0)) + skip (in place on skip buf) ------
__global__ __launch_bounds__(256) void bn_elu(
    const unsigned short* __restrict__ out0, unsigned short* __restrict__ hb,
    const float* __restrict__ scl, const float* __restrict__ sft,
    const float* __restrict__ bskip)
{
    int i = blockIdx.x * 256 + threadIdx.x;   // one per 8 elems
    if (i >= MPAD * 256 / 8) return;
    int col0 = (i * 8) & 255;
    uint4 hv = ((const uint4*)out0)[i];
    uint4 sv = ((const uint4*)hb)[i];
    float4 c0 = *(const float4*)(scl + col0);
    float4 c1 = *(const float4*)(scl + col0 + 4);
    float4 f0 = *(const float4*)(sft + col0);
    float4 f1 = *(const float4*)(sft + col0 + 4);
    float4 k0 = *(const float4*)(bskip + col0);
    float4 k1 = *(const float4*)(bskip + col0 + 4);
    float bn[8], sk[8];
    unpack2(hv.x, bn[0], bn[1]); unpack2(hv.y, bn[2], bn[3]);
    unpack2(hv.z, bn[4], bn[5]); unpack2(hv.w, bn[6], bn[7]);
    unpack2(sv.x, sk[0], sk[1]); unpack2(sv.y, sk[2], sk[3]);
    unpack2(sv.z, sk[4], sk[5]); unpack2(sv.w, sk[6], sk[7]);
    float cc[8] = {c0.x,c0.y,c0.z,c0.w,c1.x,c1.y,c1.z,c1.w};
    float ff[8] = {f0.x,f0.y,f0.z,f0.w,f1.x,f1.y,f1.z,f1.w};
    float kk[8] = {k0.x,k0.y,k0.z,k0.w,k1.x,k1.y,k1.z,k1.w};
    float r[8];
    #pragma unroll
    for (int q = 0; q < 8; q++) {
        float b = bn[q] * cc[q] + ff[q];
        float el = b > 0.f ? b : (__expf(b) - 1.f);
        r[q] = el + sk[q] + kk[q];
    }
    uint4 o;
    o.x = pack2(r[0], r[1]); o.y = pack2(r[2], r[3]);
    o.z = pack2(r[4], r[5]); o.w = pack2(r[6], r[7]);
    ((uint4*)hb)[i] = o;
}

// ---------------- gather1: half-wave edges (1 head), +b1, f32 out ----------------
__global__ __launch_bounds__(256) void gather1(
    const int* __restrict__ adj, const int* __restrict__ rowptr,
    const unsigned short* __restrict__ xp, const float* __restrict__ a_s,
    const float* __restrict__ a_d, const float* __restrict__ b1,
    float* __restrict__ out)
{
    int w = (blockIdx.x * 256 + threadIdx.x) >> 6;
    int lane = threadIdx.x & 63;
    if (w >= NN) return;
    int hl = lane & 31;
    int hw = lane >> 5;
    float ad = a_d[w];
    int p = rowptr[w], end = rowptr[w + 1];
    unsigned loff = (unsigned)hl * 16u;
    float a0=0,a1=0,a2=0,a3=0,a4=0,a5=0,a6=0,a7=0;
    float b0s=0,b1s=0,b2s=0,b3s=0,b4s=0,b5s=0,b6s=0,b7s=0;
    float den0 = 0.f, den1 = 0.f;
    for (; p + 4 <= end; p += 4) {
        int sA = adj[p + hw];
        int sB = adj[p + 2 + hw];
        float eA = a_s[sA] + ad;
        float eB = a_s[sB] + ad;
        float wA = __builtin_amdgcn_exp2f(fmaxf(eA, 0.2f * eA));
        float wB = __builtin_amdgcn_exp2f(fmaxf(eB, 0.2f * eB));
        uint4 rA = *(const uint4*)((const char*)xp + ((unsigned)sA * 512u + loff));
        uint4 rB = *(const uint4*)((const char*)xp + ((unsigned)sB * 512u + loff));
        den0 += wA; den1 += wB;
        float lo, hi;
        unpack2(rA.x, lo, hi); a0 += wA * lo; a1 += wA * hi;
        unpack2(rA.y, lo, hi); a2 += wA * lo; a3 += wA * hi;
        unpack2(rA.z, lo, hi); a4 += wA * lo; a5 += wA * hi;
        unpack2(rA.w, lo, hi); a6 += wA * lo; a7 += wA * hi;
        unpack2(rB.x, lo, hi); b0s += wB * lo; b1s += wB * hi;
        unpack2(rB.y, lo, hi); b2s += wB * lo; b3s += wB * hi;
        unpack2(rB.z, lo, hi); b4s += wB * lo; b5s += wB * hi;
        unpack2(rB.w, lo, hi); b6s += wB * lo; b7s += wB * hi;
    }
    for (; p + 2 <= end; p += 2) {
        int sA = adj[p + hw];
        float eA = a_s[sA] + ad;
        float wA = __builtin_amdgcn_exp2f(fmaxf(eA, 0.2f * eA));
        uint4 rA = *(const uint4*)((const char*)xp + ((unsigned)sA * 512u + loff));
        den0 += wA;
        float lo, hi;
        unpack2(rA.x, lo, hi); a0 += wA * lo; a1 += wA * hi;
        unpack2(rA.y, lo, hi); a2 += wA * lo; a3 += wA * hi;
        unpack2(rA.z, lo, hi); a4 += wA * lo; a5 += wA * hi;
        unpack2(rA.w, lo, hi); a6 += wA * lo; a7 += wA * hi;
    }
    if (p < end) {
        int sA = adj[p];
        float eA = a_s[sA] + ad;
        float wA = hw ? 0.f : __builtin_amdgcn_exp2f(fmaxf(eA, 0.2f * eA));
        uint4 rA = *(const uint4*)((const char*)xp + ((unsigned)sA * 512u + loff));
        den0 += wA;
        float lo, hi;
        unpack2(rA.x, lo, hi); a0 += wA * lo; a1 += wA * hi;
        unpack2(rA.y, lo, hi); a2 += wA * lo; a3 += wA * hi;
        unpack2(rA.z, lo, hi); a4 += wA * lo; a5 += wA * hi;
        unpack2(rA.w, lo, hi); a6 += wA * lo; a7 += wA * hi;
    }
    a0 += b0s; a1 += b1s; a2 += b2s; a3 += b3s;
    a4 += b4s; a5 += b5s; a6 += b6s; a7 += b7s;
    float den = den0 + den1;
    den += __shfl_xor(den, 32);
    a0 += __shfl_xor(a0, 32); a1 += __shfl_xor(a1, 32);
    a2 += __shfl_xor(a2, 32); a3 += __shfl_xor(a3, 32);
    a4 += __shfl_xor(a4, 32); a5 += __shfl_xor(a5, 32);
    a6 += __shfl_xor(a6, 32); a7 += __shfl_xor(a7, 32);
    if (hw == 0) {
        float inv = 1.f / (den + 1e-16f);
        const float* bb = b1 + hl * 8;
        float4 o0 = {a0 * inv + bb[0], a1 * inv + bb[1],
                     a2 * inv + bb[2], a3 * inv + bb[3]};
        float4 o1 = {a4 * inv + bb[4], a5 * inv + bb[5],
                     a6 * inv + bb[6], a7 * inv + bb[7]};
        float* orow = out + (size_t)w * 256 + hl * 8;
        *(float4*)(orow) = o0;
        *(float4*)(orow + 4) = o1;
    }
}

extern "C" void kernel_launch(void* const* d_in, const int* in_sizes, int n_in,
                              void* d_out, int out_size, void* d_ws, size_t ws_size,
                              hipStream_t stream)
{
    const float* x      = (const float*)d_in[0];
    const int*   ei     = (const int*)d_in[1];
    const float* W0     = (const float*)d_in[2];
    const float* att_s0 = (const float*)d_in[3];
    const float* att_d0 = (const float*)d_in[4];
    // b0 (d_in[5]) cancels under BatchNorm -> unused
    const float* gamma0 = (const float*)d_in[6];
    const float* beta0  = (const float*)d_in[7];
    const float* W_skip = (const float*)d_in[8];
    const float* b_skip = (const float*)d_in[9];
    const float* W1     = (const float*)d_in[10];
    const float* att_s1 = (const float*)d_in[11];
    const float* att_d1 = (const float*)d_in[12];
    const float* b1     = (const float*)d_in[13];
    float* out = (float*)d_out;

    // workspace layout
    char* p = (char*)d_ws;
    unsigned short* x_bf  = (unsigned short*)p; p += (size_t)MPAD * 128 * 2;
    unsigned short* xp_bf = (unsigned short*)p; p += (size_t)MPAD * 256 * 2;  // xp0 then xp1
    unsigned short* h_bf  = (unsigned short*)p; p += (size_t)MPAD * 256 * 2;  // skip, then h in place
    unsigned short* out0b = (unsigned short*)p; p += (size_t)MPAD * 256 * 2;
    unsigned short* Wtc   = (unsigned short*)p; p += (size_t)512 * 128 * 2;   // [W0t | Wst]
    unsigned short* W1t   = (unsigned short*)p; p += (size_t)256 * 256 * 2;
    float* a_s   = (float*)p; p += (size_t)NN * 8 * 4;
    float* a_d   = (float*)p; p += (size_t)NN * 8 * 4;
    float* bnsum = (float*)p; p += 256 * 4;
    float* bnsq  = (float*)p; p += 256 * 4;
    float* scl   = (float*)p; p += 256 * 4;
    float* sft   = (float*)p; p += 256 * 4;
    int* deg    = (int*)p; p += (size_t)NN * 4;
    int* rowptr = (int*)p; p += (size_t)(NN + 1) * 4;
    int* cursor = (int*)p; p += (size_t)NN * 4;
    int* adj    = (int*)p; p += (size_t)ET * 4;

    hipMemsetAsync(deg, 0, (size_t)NN * 4, stream);
    hipMemsetAsync(bnsum, 0, 512 * 4, stream);
    // deterministic pad rows for out0b (never written by gather0)
    hipMemsetAsync(out0b + (size_t)NN * 256, 0, (size_t)(MPAD - NN) * 256 * 2, stream);

    // converts
    conv_x<<<(MPAD * 128 / 4 + 255) / 256, 256, 0, stream>>>(x, x_bf);
    conv_wt<<<(128 * 256 + 255) / 256, 256, 0, stream>>>(W0, Wtc, 128);
    conv_wt<<<(128 * 256 + 255) / 256, 256, 0, stream>>>(W_skip, Wtc + 256 * 128, 128);
    conv_wt<<<(256 * 256 + 255) / 256, 256, 0, stream>>>(W1, W1t, 256);

    // CSR build
    csr_count<<<(ET + 255) / 256, 256, 0, stream>>>(ei, deg);
    exscan<<<1, 1024, 0, stream>>>(deg, rowptr, cursor);
    csr_fill<<<(ET + 255) / 256, 256, 0, stream>>>(ei, cursor, adj);

    // ---- layer 0: combined GEMM (xp | skip) ----
    dim3 gg0(MPAD / 128, 4);
    gemm_bf16<<<gg0, 256, 0, stream>>>(x_bf, Wtc, xp_bf, h_bf, 128);
    attn_node0<<<(NN * 8 + 255) / 256, 256, 0, stream>>>(xp_bf, att_s0, att_d0, a_s, a_d);
    gather0<<<(NN * 64 + 255) / 256, 256, 0, stream>>>(adj, rowptr, xp_bf, a_s, a_d, out0b);

    // ---- BN + ELU + skip (elementwise, in place on h_bf) ----
    bn_stats<<<NN / 64, 256, 0, stream>>>(out0b, bnsum, bnsq);
    bn_coef<<<1, 256, 0, stream>>>(bnsum, bnsq, gamma0, beta0, scl, sft);
    bn_elu<<<(MPAD * 256 / 8 + 255) / 256, 256, 0, stream>>>(out0b, h_bf, scl, sft, b_skip);

    // ---- layer 1 ----
    dim3 gg1(MPAD / 128, 2);
    gemm_bf16<<<gg1, 256, 0, stream>>>(h_bf, W1t, xp_bf, xp_bf, 256);
    attn_node1<<<(NN * 64 + 255) / 256, 256, 0, stream>>>(xp_bf, att_s1, att_d1, a_s, a_d);
    gather1<<<(NN * 64 + 255) / 256, 256, 0, stream>>>(adj, rowptr, xp_bf, a_s, a_d, b1, out);
}

// Round 8
// 321.610 us; speedup vs baseline: 1.6496x; 1.0165x over previous
//
#include <hip/hip_runtime.h>
#include <hip/hip_bf16.h>

#define NN 40000
#define EE 640000
#define ET 680000   // EE + NN self loops
#define MPAD 40064  // 313 * 128
#define LOG2E 1.4426950408889634f

typedef __attribute__((ext_vector_type(8))) short short8;
typedef __attribute__((ext_vector_type(4))) float f32x4;

__device__ __forceinline__ float bf2f(unsigned u) {
    return __uint_as_float(u << 16);
}
__device__ __forceinline__ unsigned short f2bf(float f) {
    unsigned u = __float_as_uint(f);
    return (unsigned short)((u + 0x7FFFu + ((u >> 16) & 1u)) >> 16);
}
__device__ __forceinline__ unsigned pack2(float lo, float hi) {
    return ((unsigned)f2bf(lo)) | (((unsigned)f2bf(hi)) << 16);
}
__device__ __forceinline__ void unpack2(unsigned u, float& lo, float& hi) {
    lo = __uint_as_float(u << 16);
    hi = __uint_as_float(u & 0xffff0000u);
}

// ---------------- converts ----------------
__global__ __launch_bounds__(256) void conv_x(const float* __restrict__ x,
                                              unsigned short* __restrict__ xb)
{
    int i = blockIdx.x * 256 + threadIdx.x;          // one per 4 elems
    if (i >= MPAD * 128 / 4) return;
    int row = (i * 4) >> 7;
    ushort4 o;
    if (row < NN) {
        float4 v = ((const float4*)x)[i];
        o.x = f2bf(v.x); o.y = f2bf(v.y); o.z = f2bf(v.z); o.w = f2bf(v.w);
    } else { o.x = o.y = o.z = o.w = 0; }
    ((ushort4*)xb)[i] = o;
}

// all three weight transposes in one launch:
//   i in [0,32768)        : W0 [128][256] -> Wtc[256][128]
//   i in [32768,65536)    : W_skip        -> Wtc+32768
//   i in [65536,131072)   : W1 [256][256] -> W1t[256][256]
__global__ __launch_bounds__(256) void conv_wt_all(
    const float* __restrict__ W0, const float* __restrict__ Ws,
    const float* __restrict__ W1, unsigned short* __restrict__ Wtc,
    unsigned short* __restrict__ W1t)
{
    int i = blockIdx.x * 256 + threadIdx.x;
    if (i < 32768) {
        int c = i >> 7, k = i & 127;
        Wtc[i] = f2bf(W0[(size_t)k * 256 + c]);
    } else if (i < 65536) {
        int j = i - 32768;
        int c = j >> 7, k = j & 127;
        Wtc[i] = f2bf(Ws[(size_t)k * 256 + c]);
    } else if (i < 131072) {
        int j = i - 65536;
        int c = j >> 8, k = j & 255;
        W1t[j] = f2bf(W1[(size_t)k * 256 + c]);
    }
}

// ---------------- MFMA GEMM: Cd[MPAD][256] = A[MPAD][K] @ Bt^T (dual output) ----------
__global__ __launch_bounds__(256) void gemm_bf16(
    const unsigned short* __restrict__ A, const unsigned short* __restrict__ Btc,
    unsigned short* __restrict__ C0, unsigned short* __restrict__ C1, int K)
{
    __shared__ unsigned short As[128 * 64];
    int tid = threadIdx.x;
    int rb = blockIdx.x * 128, cb = blockIdx.y * 128;
    int lane = tid & 63, wid = tid >> 6;
    int wm = (wid >> 1) * 64, wn = (wid & 1) * 64;
    int lr = lane & 15, lk = lane >> 4;
    f32x4 acc[4][4] = {};
    for (int kb = 0; kb < K; kb += 64) {
        #pragma unroll
        for (int i = 0; i < 4; i++) {
            int flat = tid + i * 256;
            int r = flat >> 3, c8 = flat & 7;
            int4 v = *(const int4*)(A + (size_t)(rb + r) * K + kb + c8 * 8);
            *(int4*)(&As[r * 64 + ((c8 ^ (r & 7)) * 8)]) = v;
        }
        __syncthreads();
        #pragma unroll
        for (int kk = 0; kk < 2; kk++) {
            int kbase = kb + kk * 32 + lk * 8;
            short8 bfr[4], afr[4];
            #pragma unroll
            for (int n = 0; n < 4; n++)
                bfr[n] = *(const short8*)(Btc + (size_t)(cb + wn + n * 16 + lr) * K + kbase);
            #pragma unroll
            for (int m = 0; m < 4; m++) {
                int row = wm + m * 16 + lr;
                int kchunk = kk * 4 + lk;
                afr[m] = *(const short8*)(&As[row * 64 + ((kchunk ^ (row & 7)) * 8)]);
            }
            #pragma unroll
            for (int m = 0; m < 4; m++)
                #pragma unroll
                for (int n = 0; n < 4; n++)
                    acc[m][n] = __builtin_amdgcn_mfma_f32_16x16x32_bf16(afr[m], bfr[n], acc[m][n], 0, 0, 0);
        }
        __syncthreads();
    }
    unsigned short* C = (cb < 256) ? C0 : C1;
    int cbase = cb & 255;
    #pragma unroll
    for (int m = 0; m < 4; m++)
        #pragma unroll
        for (int n = 0; n < 4; n++) {
            int col = cbase + wn + n * 16 + lr;
            #pragma unroll
            for (int j = 0; j < 4; j++) {
                int row = rb + wm + m * 16 + lk * 4 + j;
                C[(size_t)row * 256 + col] = f2bf(acc[m][n][j]);
            }
        }
}

// ---------------- CSR build (by dst) ----------------
__global__ __launch_bounds__(256) void csr_count(const int* __restrict__ ei, int* __restrict__ deg)
{
    int e = blockIdx.x * blockDim.x + threadIdx.x;
    if (e >= ET) return;
    int d = (e < EE) ? ei[EE + e] : (e - EE);
    atomicAdd(&deg[d], 1);
}

__global__ __launch_bounds__(1024) void exscan(
    const int* __restrict__ deg, int* __restrict__ rowptr, int* __restrict__ cursor)
{
    __shared__ int wsum[16];
    __shared__ int carry_s;
    int tid = threadIdx.x, lane = tid & 63, wid = tid >> 6;
    if (tid == 0) carry_s = 0;
    __syncthreads();
    for (int base = 0; base < NN; base += 1024) {
        int i = base + tid;
        int v = (i < NN) ? deg[i] : 0;
        int sc = v;
        #pragma unroll
        for (int off = 1; off < 64; off <<= 1) {
            int t = __shfl_up(sc, off);
            if (lane >= off) sc += t;
        }
        if (lane == 63) wsum[wid] = sc;
        __syncthreads();
        if (wid == 0 && lane < 16) {
            int t = wsum[lane];
            #pragma unroll
            for (int off = 1; off < 16; off <<= 1) {
                int u = __shfl_up(t, off);
                if (lane >= off) t += u;
            }
            wsum[lane] = t;
        }
        __syncthreads();
        int carry = carry_s;
        int wpre = wid ? wsum[wid - 1] : 0;
        int excl = carry + wpre + sc - v;
        if (i < NN) { rowptr[i] = excl; cursor[i] = excl; }
        __syncthreads();
        if (tid == 0) carry_s = carry + wsum[15];
    }
    if (tid == 0) rowptr[NN] = carry_s;
}

__global__ __launch_bounds__(256) void csr_fill(
    const int* __restrict__ ei, int* __restrict__ cursor, int* __restrict__ adj)
{
    int e = blockIdx.x * blockDim.x + threadIdx.x;
    if (e >= ET) return;
    int s, d;
    if (e < EE) { s = ei[e]; d = ei[EE + e]; } else { s = d = e - EE; }
    int pos = atomicAdd(&cursor[d], 1);
    adj[pos] = s;
}

// ---------------- attention logits (pre-scaled by log2(e)) ----------------
__global__ __launch_bounds__(256) void attn_node0(
    const unsigned short* __restrict__ xp, const float* __restrict__ att_s,
    const float* __restrict__ att_d, float* __restrict__ a_s, float* __restrict__ a_d)
{
    int t = blockIdx.x * 256 + threadIdx.x;
    if (t >= NN * 8) return;
    int n = t >> 3, h = t & 7;
    const unsigned short* p = xp + (size_t)n * 256 + h * 32;
    float s = 0.f, dd = 0.f;
    #pragma unroll
    for (int i0 = 0; i0 < 32; i0 += 8) {
        uint4 raw = *(const uint4*)(p + i0);
        unsigned vals[4] = {raw.x, raw.y, raw.z, raw.w};
        #pragma unroll
        for (int q = 0; q < 4; q++) {
            float lo, hi;
            unpack2(vals[q], lo, hi);
            s  += lo * att_s[h * 32 + i0 + q * 2] + hi * att_s[h * 32 + i0 + q * 2 + 1];
            dd += lo * att_d[h * 32 + i0 + q * 2] + hi * att_d[h * 32 + i0 + q * 2 + 1];
        }
    }
    a_s[t] = s * LOG2E; a_d[t] = dd * LOG2E;
}

__global__ __launch_bounds__(256) void attn_node1(
    const unsigned short* __restrict__ xp, const float* __restrict__ att_s,
    const float* __restrict__ att_d, float* __restrict__ a_s, float* __restrict__ a_d)
{
    int w = (blockIdx.x * 256 + threadIdx.x) >> 6;
    int lane = threadIdx.x & 63;
    if (w >= NN) return;
    ushort4 raw = ((const ushort4*)(xp + (size_t)w * 256))[lane];
    float4 a = ((const float4*)att_s)[lane];
    float4 b = ((const float4*)att_d)[lane];
    float v0 = bf2f(raw.x), v1 = bf2f(raw.y), v2 = bf2f(raw.z), v3 = bf2f(raw.w);
    float s  = v0 * a.x + v1 * a.y + v2 * a.z + v3 * a.w;
    float dd = v0 * b.x + v1 * b.y + v2 * b.z + v3 * b.w;
    #pragma unroll
    for (int off = 32; off; off >>= 1) {
        s  += __shfl_down(s, off);
        dd += __shfl_down(dd, off);
    }
    if (lane == 0) { a_s[w] = s * LOG2E; a_d[w] = dd * LOG2E; }
}

// ---------------- gather0: half-wave edges, 8 ch/lane, 8 edges in flight ------------
__global__ __launch_bounds__(256) void gather0(
    const int* __restrict__ adj, const int* __restrict__ rowptr,
    const unsigned short* __restrict__ xp, const float* __restrict__ a_s,
    const float* __restrict__ a_d, unsigned short* __restrict__ out0)
{
    int w = (blockIdx.x * 256 + threadIdx.x) >> 6;
    int lane = threadIdx.x & 63;
    if (w >= NN) return;
    int hl = lane & 31;               // half-lane
    int hw = lane >> 5;               // which half-wave
    int h = hl >> 2;                  // head = (8*hl)/32
    float ad = a_d[w * 8 + h];
    int p = rowptr[w], end = rowptr[w + 1];
    unsigned loff = (unsigned)hl * 16u;
    float a0=0,a1=0,a2=0,a3=0,a4=0,a5=0,a6=0,a7=0;
    float b0=0,b1=0,b2=0,b3=0,b4=0,b5=0,b6=0,b7=0;
    float den0 = 0.f, den1 = 0.f;
    float lo, hi;
    for (; p + 8 <= end; p += 8) {
        int sA = adj[p + hw];
        int sB = adj[p + 2 + hw];
        int sC = adj[p + 4 + hw];
        int sD = adj[p + 6 + hw];
        float eA = a_s[sA * 8 + h] + ad;
        float eB = a_s[sB * 8 + h] + ad;
        float eC = a_s[sC * 8 + h] + ad;
        float eD = a_s[sD * 8 + h] + ad;
        float wA = __builtin_amdgcn_exp2f(fmaxf(eA, 0.2f * eA));
        float wB = __builtin_amdgcn_exp2f(fmaxf(eB, 0.2f * eB));
        float wC = __builtin_amdgcn_exp2f(fmaxf(eC, 0.2f * eC));
        float wD = __builtin_amdgcn_exp2f(fmaxf(eD, 0.2f * eD));
        uint4 rA = *(const uint4*)((const char*)xp + ((unsigned)sA * 512u + loff));
        uint4 rB = *(const uint4*)((const char*)xp + ((unsigned)sB * 512u + loff));
        uint4 rC = *(const uint4*)((const char*)xp + ((unsigned)sC * 512u + loff));
        uint4 rD = *(const uint4*)((const char*)xp + ((unsigned)sD * 512u + loff));
        den0 += wA + wC; den1 += wB + wD;
        unpack2(rA.x, lo, hi); a0 += wA * lo; a1 += wA * hi;
        unpack2(rA.y, lo, hi); a2 += wA * lo; a3 += wA * hi;
        unpack2(rA.z, lo, hi); a4 += wA * lo; a5 += wA * hi;
        unpack2(rA.w, lo, hi); a6 += wA * lo; a7 += wA * hi;
        unpack2(rB.x, lo, hi); b0 += wB * lo; b1 += wB * hi;
        unpack2(rB.y, lo, hi); b2 += wB * lo; b3 += wB * hi;
        unpack2(rB.z, lo, hi); b4 += wB * lo; b5 += wB * hi;
        unpack2(rB.w, lo, hi); b6 += wB * lo; b7 += wB * hi;
        unpack2(rC.x, lo, hi); a0 += wC * lo; a1 += wC * hi;
        unpack2(rC.y, lo, hi); a2 += wC * lo; a3 += wC * hi;
        unpack2(rC.z, lo, hi); a4 += wC * lo; a5 += wC * hi;
        unpack2(rC.w, lo, hi); a6 += wC * lo; a7 += wC * hi;
        unpack2(rD.x, lo, hi); b0 += wD * lo; b1 += wD * hi;
        unpack2(rD.y, lo, hi); b2 += wD * lo; b3 += wD * hi;
        unpack2(rD.z, lo, hi); b4 += wD * lo; b5 += wD * hi;
        unpack2(rD.w, lo, hi); b6 += wD * lo; b7 += wD * hi;
    }
    for (; p + 2 <= end; p += 2) {
        int sA = adj[p + hw];
        float eA = a_s[sA * 8 + h] + ad;
        float wA = __builtin_amdgcn_exp2f(fmaxf(eA, 0.2f * eA));
        uint4 rA = *(const uint4*)((const char*)xp + ((unsigned)sA * 512u + loff));
        den0 += wA;
        unpack2(rA.x, lo, hi); a0 += wA * lo; a1 += wA * hi;
        unpack2(rA.y, lo, hi); a2 += wA * lo; a3 += wA * hi;
        unpack2(rA.z, lo, hi); a4 += wA * lo; a5 += wA * hi;
        unpack2(rA.w, lo, hi); a6 += wA * lo; a7 += wA * hi;
    }
    if (p < end) {                     // single tail edge: half A only
        int sA = adj[p];
        float eA = a_s[sA * 8 + h] + ad;
        float wA = hw ? 0.f : __builtin_amdgcn_exp2f(fmaxf(eA, 0.2f * eA));
        uint4 rA = *(const uint4*)((const char*)xp + ((unsigned)sA * 512u + loff));
        den0 += wA;
        unpack2(rA.x, lo, hi); a0 += wA * lo; a1 += wA * hi;
        unpack2(rA.y, lo, hi); a2 += wA * lo; a3 += wA * hi;
        unpack2(rA.z, lo, hi); a4 += wA * lo; a5 += wA * hi;
        unpack2(rA.w, lo, hi); a6 += wA * lo; a7 += wA * hi;
    }
    a0 += b0; a1 += b1; a2 += b2; a3 += b3;
    a4 += b4; a5 += b5; a6 += b6; a7 += b7;
    float den = den0 + den1;
    den += __shfl_xor(den, 32);
    a0 += __shfl_xor(a0, 32); a1 += __shfl_xor(a1, 32);
    a2 += __shfl_xor(a2, 32); a3 += __shfl_xor(a3, 32);
    a4 += __shfl_xor(a4, 32); a5 += __shfl_xor(a5, 32);
    a6 += __shfl_xor(a6, 32); a7 += __shfl_xor(a7, 32);
    if (hw == 0) {
        float inv = 1.f / (den + 1e-16f);
        uint4 o;
        o.x = pack2(a0 * inv, a1 * inv);
        o.y = pack2(a2 * inv, a3 * inv);
        o.z = pack2(a4 * inv, a5 * inv);
        o.w = pack2(a6 * inv, a7 * inv);
        *(uint4*)((char*)out0 + ((size_t)w * 512u + loff)) = o;
    }
}

// ---------------- BN column stats (bf16 input, standalone) ----------------
__global__ __launch_bounds__(256) void bn_stats(
    const unsigned short* __restrict__ H, float* __restrict__ bnsum, float* __restrict__ bnsq)
{
    int c = threadIdx.x;
    int r0 = blockIdx.x * 64;
    float s = 0.f, sq = 0.f;
    for (int r = r0; r < r0 + 64; r++) {
        float v = bf2f(H[(size_t)r * 256 + c]);
        s += v; sq += v * v;
    }
    atomicAdd(&bnsum[c], s);
    atomicAdd(&bnsq[c], sq);
}

// ---------------- elementwise: h = elu(bn(out0)) + skip (coef computed inline) ------
__global__ __launch_bounds__(256) void bn_elu(
    const unsigned short* __restrict__ out0, unsigned short* __restrict__ hb,
    const float* __restrict__ bnsum, const float* __restrict__ bnsq,
    const float* __restrict__ gamma, const float* __restrict__ beta,
    const float* __restrict__ bskip)
{
    int i = blockIdx.x * 256 + threadIdx.x;   // one per 8 elems
    if (i >= MPAD * 256 / 8) return;
    int col0 = (i * 8) & 255;
    uint4 hv = ((const uint4*)out0)[i];
    uint4 sv = ((const uint4*)hb)[i];
    float bn[8], sk[8];
    unpack2(hv.x, bn[0], bn[1]); unpack2(hv.y, bn[2], bn[3]);
    unpack2(hv.z, bn[4], bn[5]); unpack2(hv.w, bn[6], bn[7]);
    unpack2(sv.x, sk[0], sk[1]); unpack2(sv.y, sk[2], sk[3]);
    unpack2(sv.z, sk[4], sk[5]); unpack2(sv.w, sk[6], sk[7]);
    const float invN = 1.0f / (float)NN;
    float r[8];
    #pragma unroll
    for (int q = 0; q < 8; q++) {
        int c = col0 + q;
        float mu = bnsum[c] * invN;
        float var = bnsq[c] * invN - mu * mu;
        float scl = rsqrtf(var + 1e-5f) * gamma[c];
        float b = (bn[q] - mu) * scl + beta[c];
        float el = b > 0.f ? b : (__expf(b) - 1.f);
        r[q] = el + sk[q] + bskip[c];
    }
    uint4 o;
    o.x = pack2(r[0], r[1]); o.y = pack2(r[2], r[3]);
    o.z = pack2(r[4], r[5]); o.w = pack2(r[6], r[7]);
    ((uint4*)hb)[i] = o;
}

// ---------------- gather1: half-wave edges (1 head), 8 in flight, +b1, f32 out ------
__global__ __launch_bounds__(256) void gather1(
    const int* __restrict__ adj, const int* __restrict__ rowptr,
    const unsigned short* __restrict__ xp, const float* __restrict__ a_s,
    const float* __restrict__ a_d, const float* __restrict__ b1,
    float* __restrict__ out)
{
    int w = (blockIdx.x * 256 + threadIdx.x) >> 6;
    int lane = threadIdx.x & 63;
    if (w >= NN) return;
    int hl = lane & 31;
    int hw = lane >> 5;
    float ad = a_d[w];
    int p = rowptr[w], end = rowptr[w + 1];
    unsigned loff = (unsigned)hl * 16u;
    float a0=0,a1=0,a2=0,a3=0,a4=0,a5=0,a6=0,a7=0;
    float b0s=0,b1s=0,b2s=0,b3s=0,b4s=0,b5s=0,b6s=0,b7s=0;
    float den0 = 0.f, den1 = 0.f;
    float lo, hi;
    for (; p + 8 <= end; p += 8) {
        int sA = adj[p + hw];
        int sB = adj[p + 2 + hw];
        int sC = adj[p + 4 + hw];
        int sD = adj[p + 6 + hw];
        float eA = a_s[sA] + ad;
        float eB = a_s[sB] + ad;
        float eC = a_s[sC] + ad;
        float eD = a_s[sD] + ad;
        float wA = __builtin_amdgcn_exp2f(fmaxf(eA, 0.2f * eA));
        float wB = __builtin_amdgcn_exp2f(fmaxf(eB, 0.2f * eB));
        float wC = __builtin_amdgcn_exp2f(fmaxf(eC, 0.2f * eC));
        float wD = __builtin_amdgcn_exp2f(fmaxf(eD, 0.2f * eD));
        uint4 rA = *(const uint4*)((const char*)xp + ((unsigned)sA * 512u + loff));
        uint4 rB = *(const uint4*)((const char*)xp + ((unsigned)sB * 512u + loff));
        uint4 rC = *(const uint4*)((const char*)xp + ((unsigned)sC * 512u + loff));
        uint4 rD = *(const uint4*)((const char*)xp + ((unsigned)sD * 512u + loff));
        den0 += wA + wC; den1 += wB + wD;
        unpack2(rA.x, lo, hi); a0 += wA * lo; a1 += wA * hi;
        unpack2(rA.y, lo, hi); a2 += wA * lo; a3 += wA * hi;
        unpack2(rA.z, lo, hi); a4 += wA * lo; a5 += wA * hi;
        unpack2(rA.w, lo, hi); a6 += wA * lo; a7 += wA * hi;
        unpack2(rB.x, lo, hi); b0s += wB * lo; b1s += wB * hi;
        unpack2(rB.y, lo, hi); b2s += wB * lo; b3s += wB * hi;
        unpack2(rB.z, lo, hi); b4s += wB * lo; b5s += wB * hi;
        unpack2(rB.w, lo, hi); b6s += wB * lo; b7s += wB * hi;
        unpack2(rC.x, lo, hi); a0 += wC * lo; a1 += wC * hi;
        unpack2(rC.y, lo, hi); a2 += wC * lo; a3 += wC * hi;
        unpack2(rC.z, lo, hi); a4 += wC * lo; a5 += wC * hi;
        unpack2(rC.w, lo, hi); a6 += wC * lo; a7 += wC * hi;
        unpack2(rD.x, lo, hi); b0s += wD * lo; b1s += wD * hi;
        unpack2(rD.y, lo, hi); b2s += wD * lo; b3s += wD * hi;
        unpack2(rD.z, lo, hi); b4s += wD * lo; b5s += wD * hi;
        unpack2(rD.w, lo, hi); b6s += wD * lo; b7s += wD * hi;
    }
    for (; p + 2 <= end; p += 2) {
        int sA = adj[p + hw];
        float eA = a_s[sA] + ad;
        float wA = __builtin_amdgcn_exp2f(fmaxf(eA, 0.2f * eA));
        uint4 rA = *(const uint4*)((const char*)xp + ((unsigned)sA * 512u + loff));
        den0 += wA;
        unpack2(rA.x, lo, hi); a0 += wA * lo; a1 += wA * hi;
        unpack2(rA.y, lo, hi); a2 += wA * lo; a3 += wA * hi;
        unpack2(rA.z, lo, hi); a4 += wA * lo; a5 += wA * hi;
        unpack2(rA.w, lo, hi); a6 += wA * lo; a7 += wA * hi;
    }
    if (p < end) {
        int sA = adj[p];
        float eA = a_s[sA] + ad;
        float wA = hw ? 0.f : __builtin_amdgcn_exp2f(fmaxf(eA, 0.2f * eA));
        uint4 rA = *(const uint4*)((const char*)xp + ((unsigned)sA * 512u + loff));
        den0 += wA;
        unpack2(rA.x, lo, hi); a0 += wA * lo; a1 += wA * hi;
        unpack2(rA.y, lo, hi); a2 += wA * lo; a3 += wA * hi;
        unpack2(rA.z, lo, hi); a4 += wA * lo; a5 += wA * hi;
        unpack2(rA.w, lo, hi); a6 += wA * lo; a7 += wA * hi;
    }
    a0 += b0s; a1 += b1s; a2 += b2s; a3 += b3s;
    a4 += b4s; a5 += b5s; a6 += b6s; a7 += b7s;
    float den = den0 + den1;
    den += __shfl_xor(den, 32);
    a0 += __shfl_xor(a0, 32); a1 += __shfl_xor(a1, 32);
    a2 += __shfl_xor(a2, 32); a3 += __shfl_xor(a3, 32);
    a4 += __shfl_xor(a4, 32); a5 += __shfl_xor(a5, 32);
    a6 += __shfl_xor(a6, 32); a7 += __shfl_xor(a7, 32);
    if (hw == 0) {
        float inv = 1.f / (den + 1e-16f);
        const float* bb = b1 + hl * 8;
        float4 o0 = {a0 * inv + bb[0], a1 * inv + bb[1],
                     a2 * inv + bb[2], a3 * inv + bb[3]};
        float4 o1 = {a4 * inv + bb[4], a5 * inv + bb[5],
                     a6 * inv + bb[6], a7 * inv + bb[7]};
        float* orow = out + (size_t)w * 256 + hl * 8;
        *(float4*)(orow) = o0;
        *(float4*)(orow + 4) = o1;
    }
}

extern "C" void kernel_launch(void* const* d_in, const int* in_sizes, int n_in,
                              void* d_out, int out_size, void* d_ws, size_t ws_size,
                              hipStream_t stream)
{
    const float* x      = (const float*)d_in[0];
    const int*   ei     = (const int*)d_in[1];
    const float* W0     = (const float*)d_in[2];
    const float* att_s0 = (const float*)d_in[3];
    const float* att_d0 = (const float*)d_in[4];
    // b0 (d_in[5]) cancels under BatchNorm -> unused
    const float* gamma0 = (const float*)d_in[6];
    const float* beta0  = (const float*)d_in[7];
    const float* W_skip = (const float*)d_in[8];
    const float* b_skip = (const float*)d_in[9];
    const float* W1     = (const float*)d_in[10];
    const float* att_s1 = (const float*)d_in[11];
    const float* att_d1 = (const float*)d_in[12];
    const float* b1     = (const float*)d_in[13];
    float* out = (float*)d_out;

    // workspace layout
    char* p = (char*)d_ws;
    unsigned short* x_bf  = (unsigned short*)p; p += (size_t)MPAD * 128 * 2;
    unsigned short* xp_bf = (unsigned short*)p; p += (size_t)MPAD * 256 * 2;  // xp0 then xp1
    unsigned short* h_bf  = (unsigned short*)p; p += (size_t)MPAD * 256 * 2;  // skip, then h in place
    unsigned short* out0b = (unsigned short*)p; p += (size_t)MPAD * 256 * 2;
    unsigned short* Wtc   = (unsigned short*)p; p += (size_t)512 * 128 * 2;   // [W0t | Wst]
    unsigned short* W1t   = (unsigned short*)p; p += (size_t)256 * 256 * 2;
    float* a_s   = (float*)p; p += (size_t)NN * 8 * 4;
    float* a_d   = (float*)p; p += (size_t)NN * 8 * 4;
    float* bnsum = (float*)p; p += 256 * 4;
    float* bnsq  = (float*)p; p += 256 * 4;
    int* deg    = (int*)p; p += (size_t)NN * 4;
    int* rowptr = (int*)p; p += (size_t)(NN + 1) * 4;
    int* cursor = (int*)p; p += (size_t)NN * 4;
    int* adj    = (int*)p; p += (size_t)ET * 4;

    hipMemsetAsync(deg, 0, (size_t)NN * 4, stream);
    hipMemsetAsync(bnsum, 0, 512 * 4, stream);
    // deterministic pad rows for out0b (never written by gather0)
    hipMemsetAsync(out0b + (size_t)NN * 256, 0, (size_t)(MPAD - NN) * 256 * 2, stream);

    // converts
    conv_x<<<(MPAD * 128 / 4 + 255) / 256, 256, 0, stream>>>(x, x_bf);
    conv_wt_all<<<(131072 + 255) / 256, 256, 0, stream>>>(W0, W_skip, W1, Wtc, W1t);

    // CSR build
    csr_count<<<(ET + 255) / 256, 256, 0, stream>>>(ei, deg);
    exscan<<<1, 1024, 0, stream>>>(deg, rowptr, cursor);
    csr_fill<<<(ET + 255) / 256, 256, 0, stream>>>(ei, cursor, adj);

    // ---- layer 0: combined GEMM (xp | skip) ----
    dim3 gg0(MPAD / 128, 4);
    gemm_bf16<<<gg0, 256, 0, stream>>>(x_bf, Wtc, xp_bf, h_bf, 128);
    attn_node0<<<(NN * 8 + 255) / 256, 256, 0, stream>>>(xp_bf, att_s0, att_d0, a_s, a_d);
    gather0<<<(NN * 64 + 255) / 256, 256, 0, stream>>>(adj, rowptr, xp_bf, a_s, a_d, out0b);

    // ---- BN + ELU + skip (elementwise, in place on h_bf) ----
    bn_stats<<<NN / 64, 256, 0, stream>>>(out0b, bnsum, bnsq);
    bn_elu<<<(MPAD * 256 / 8 + 255) / 256, 256, 0, stream>>>(out0b, h_bf, bnsum, bnsq,
                                                             gamma0, beta0, b_skip);

    // ---- layer 1 ----
    dim3 gg1(MPAD / 128, 2);
    gemm_bf16<<<gg1, 256, 0, stream>>>(h_bf, W1t, xp_bf, xp_bf, 256);
    attn_node1<<<(NN * 64 + 255) / 256, 256, 0, stream>>>(xp_bf, att_s1, att_d1, a_s, a_d);
    gather1<<<(NN * 64 + 255) / 256, 256, 0, stream>>>(adj, rowptr, xp_bf, a_s, a_d, b1, out);
}